// Round 2
// baseline (2188.202 us; speedup 1.0000x reference)
//
#include <hip/hip_runtime.h>
#include <hip/hip_bf16.h>
#include <math.h>

// Problem dims
#define BB 8
#define TT 4096
#define DD 256
#define INNER 512
#define SS 16
#define MTOK (BB*TT)          // 32768 tokens
#define NCODE 240

#define SCAN_NC 64
#define SCAN_L  64            // TT / SCAN_NC

__device__ __forceinline__ float sigmoidf_(float x) { return 1.f / (1.f + expf(-x)); }
__device__ __forceinline__ float siluf_(float x)    { return x / (1.f + expf(-x)); }
__device__ __forceinline__ float geluf_(float x) {
    // jax.nn.gelu default approximate=True (tanh form)
    float x3 = x * x * x;
    return 0.5f * x * (1.f + tanhf(0.7978845608028654f * (x + 0.044715f * x3)));
}
__device__ __forceinline__ float softplusf_(float x) {
    return fmaxf(x, 0.f) + log1pf(expf(-fabsf(x)));
}

// ---------------------------------------------------------------------------
// Generic f32 GEMM: C[M,N] = act(A[M,K] @ W[K,N] + bias), 128x128x16 tile,
// 256 threads, 8x8 per thread. M multiple of 128; N guarded; K multiple of 16.
// ldc allows writing a column sub-range of a wider row (used for the XP alias).
// ---------------------------------------------------------------------------
template<int ACT>  // 0=none, 1=silu, 2=softplus
__global__ __launch_bounds__(256)
void gemm_bias_act(const float* __restrict__ A, int lda,
                   const float* __restrict__ W,
                   const float* __restrict__ bias,
                   float* __restrict__ C, int ldc,
                   int N, int K)
{
    __shared__ float As[16][128];
    __shared__ float Bs[16][128];
    const int tid = threadIdx.x;
    const int tx = tid & 15, ty = tid >> 4;
    const int row0 = blockIdx.y * 128;
    const int col0 = blockIdx.x * 128;

    float acc[8][8] = {};

    for (int k0 = 0; k0 < K; k0 += 16) {
        #pragma unroll
        for (int i = 0; i < 8; ++i) {
            int e = tid + i * 256;
            int r = e >> 4, kk = e & 15;
            As[kk][r] = A[(size_t)(row0 + r) * lda + k0 + kk];
        }
        #pragma unroll
        for (int i = 0; i < 8; ++i) {
            int e = tid + i * 256;
            int kk = e >> 7, c = e & 127;
            int col = col0 + c;
            Bs[kk][c] = (col < N) ? W[(size_t)(k0 + kk) * N + col] : 0.f;
        }
        __syncthreads();
        #pragma unroll
        for (int kk = 0; kk < 16; ++kk) {
            float av[8], bv[8];
            #pragma unroll
            for (int i = 0; i < 8; ++i) av[i] = As[kk][ty * 8 + i];
            #pragma unroll
            for (int j = 0; j < 8; ++j) bv[j] = Bs[kk][tx * 8 + j];
            #pragma unroll
            for (int i = 0; i < 8; ++i)
                #pragma unroll
                for (int j = 0; j < 8; ++j)
                    acc[i][j] = fmaf(av[i], bv[j], acc[i][j]);
        }
        __syncthreads();
    }

    #pragma unroll
    for (int i = 0; i < 8; ++i) {
        int row = row0 + ty * 8 + i;
        #pragma unroll
        for (int j = 0; j < 8; ++j) {
            int col = col0 + tx * 8 + j;
            if (col < N) {
                float v = acc[i][j] + bias[col];
                if (ACT == 1) v = siluf_(v);
                else if (ACT == 2) v = softplusf_(v);
                C[(size_t)row * ldc + col] = v;
            }
        }
    }
}

// ---------------------------------------------------------------------------
// Selective scan, chunked. Block = 256 threads = 16 channels x 16 states,
// one (batch-in-group, chunk, channel-block-of-16) per block.
// XP holds dt in cols 0..511 (stride 1024) and x_gate in cols 512..1023.
// ---------------------------------------------------------------------------
__global__ __launch_bounds__(256)
void scan_pass1(const float* __restrict__ XP, const float* __restrict__ xc,
                const float* __restrict__ bc, const float* __restrict__ A_log,
                float* __restrict__ Pbuf, float* __restrict__ Hbuf)
{
    __shared__ float dtS[SCAN_L][16], xS[SCAN_L][16], BS[SCAN_L][16];
    const int bid = blockIdx.x;
    const int dblk = bid & 31;
    const int c = (bid >> 5) & 63;
    const int b = bid >> 11;          // batch index within group
    const int d0 = dblk * 16;
    const int tid = threadIdx.x;
    const int row0 = b * TT + c * SCAN_L;

    for (int e = tid; e < SCAN_L * 16; e += 256) {
        int t = e >> 4, j = e & 15;
        size_t r = (size_t)(row0 + t);
        dtS[t][j] = XP[r * 1024 + d0 + j];
        xS[t][j]  = xc[r * INNER + d0 + j];
        BS[t][j]  = bc[r * 32 + j];
    }
    __syncthreads();

    const int ch = tid >> 4;
    const int s  = tid & 15;
    const float Aval = -expf(A_log[(d0 + ch) * SS + s]);
    float h = 0.f, p = 1.f;
    #pragma unroll 4
    for (int t = 0; t < SCAN_L; ++t) {
        float dtv = dtS[t][ch];
        float a = expf(dtv * Aval);
        float u = dtv * BS[t][s] * xS[t][ch];
        h = fmaf(a, h, u);
        p *= a;
    }
    size_t o = ((size_t)(b * SCAN_NC + c) * INNER + d0) * SS + tid;
    Pbuf[o] = p;
    Hbuf[o] = h;
}

__global__ __launch_bounds__(256)
void scan_pass2(const float* __restrict__ Pbuf, float* __restrict__ Hbuf)
{
    const int idx = blockIdx.x * 256 + threadIdx.x;   // Bg*8192 threads
    const int b = idx >> 13;
    const int ds = idx & 8191;
    float hin = 0.f;
    for (int c = 0; c < SCAN_NC; ++c) {
        size_t o = ((size_t)(b * SCAN_NC + c)) * (INNER * SS) + ds;
        float p = Pbuf[o], hh = Hbuf[o];
        Hbuf[o] = hin;                // becomes h_in for chunk c
        hin = fmaf(p, hin, hh);
    }
}

// pass3: replay with correct h_in, emit gated y INTO XP cols 0..511
// (overwrites the dt tile this block itself read -> safe aliasing).
__global__ __launch_bounds__(256)
void scan_pass3(float* __restrict__ XP, const float* __restrict__ xc,
                const float* __restrict__ bc, const float* __restrict__ A_log,
                const float* __restrict__ Hin)
{
    __shared__ float dtS[SCAN_L][16], xS[SCAN_L][16], BS[SCAN_L][16];
    __shared__ float CS[SCAN_L][16], GS[SCAN_L][16], ytile[SCAN_L][16];
    const int bid = blockIdx.x;
    const int dblk = bid & 31;
    const int c = (bid >> 5) & 63;
    const int b = bid >> 11;
    const int d0 = dblk * 16;
    const int tid = threadIdx.x;
    const int row0 = b * TT + c * SCAN_L;

    for (int e = tid; e < SCAN_L * 16; e += 256) {
        int t = e >> 4, j = e & 15;
        size_t r = (size_t)(row0 + t);
        dtS[t][j] = XP[r * 1024 + d0 + j];
        xS[t][j]  = xc[r * INNER + d0 + j];
        BS[t][j]  = bc[r * 32 + j];
        CS[t][j]  = bc[r * 32 + 16 + j];
        GS[t][j]  = XP[r * 1024 + 512 + d0 + j];   // x_gate
    }
    __syncthreads();

    const int ch = tid >> 4;
    const int s  = tid & 15;
    const float Aval = -expf(A_log[(d0 + ch) * SS + s]);
    size_t o = ((size_t)(b * SCAN_NC + c) * INNER + d0) * SS + tid;
    float h = Hin[o];
    #pragma unroll 4
    for (int t = 0; t < SCAN_L; ++t) {
        float dtv = dtS[t][ch];
        float a = expf(dtv * Aval);
        float u = dtv * BS[t][s] * xS[t][ch];
        h = fmaf(a, h, u);
        float yv = h * CS[t][s];
        yv += __shfl_xor(yv, 1, 16);
        yv += __shfl_xor(yv, 2, 16);
        yv += __shfl_xor(yv, 4, 16);
        yv += __shfl_xor(yv, 8, 16);
        if (s == 0) ytile[t][ch] = yv;
    }
    __syncthreads();
    for (int e = tid; e < SCAN_L * 16; e += 256) {
        int t = e >> 4, j = e & 15;
        size_t r = (size_t)(row0 + t);
        XP[r * 1024 + d0 + j] = ytile[t][j] * siluf_(GS[t][j]);  // yg over dt
    }
}

// ---------------------------------------------------------------------------
// Catastrophe head: per token risk = sigmoid(((gelu(y@W1+b1))@W2+b2)@w3+b3)
// Wave handles 8 tokens; lane j owns f1[j].
// ---------------------------------------------------------------------------
__global__ __launch_bounds__(256)
void cat_head(const float* __restrict__ y,
              const float* __restrict__ w1, const float* __restrict__ b1,
              const float* __restrict__ w2, const float* __restrict__ b2,
              const float* __restrict__ w3, const float* __restrict__ b3,
              float* __restrict__ risk)
{
    __shared__ float yS[32][256];
    const int tid = threadIdx.x;
    const int w = tid >> 6, j = tid & 63;
    const int tok0 = blockIdx.x * 32;

    for (int e = tid; e < 32 * 256; e += 256)
        yS[e >> 8][e & 255] = y[(size_t)tok0 * 256 + e];
    __syncthreads();

    float f1[8];
    #pragma unroll
    for (int m = 0; m < 8; ++m) f1[m] = b1[j];
    const int mt0 = w * 8;
    for (int k = 0; k < 256; ++k) {
        float wv = w1[k * 64 + j];
        #pragma unroll
        for (int m = 0; m < 8; ++m)
            f1[m] = fmaf(yS[mt0 + m][k], wv, f1[m]);
    }
    for (int m = 0; m < 8; ++m) {
        float g = geluf_(f1[m]);
        float f2 = (j < 32) ? b2[j] : 0.f;
        for (int k = 0; k < 64; ++k) {
            float gk = __shfl(g, k, 64);
            if (j < 32) f2 = fmaf(gk, w2[k * 32 + j], f2);
        }
        float v = (j < 32) ? f2 * w3[j] : 0.f;
        v += __shfl_xor(v, 1, 64);
        v += __shfl_xor(v, 2, 64);
        v += __shfl_xor(v, 4, 64);
        v += __shfl_xor(v, 8, 64);
        v += __shfl_xor(v, 16, 64);
        v += __shfl_xor(v, 32, 64);
        if (j == 0) risk[tok0 + mt0 + m] = sigmoidf_(v + b3[0]);
    }
}

// ---------------------------------------------------------------------------
// E8 head: e8c = gelu(y@Wa+ba)@Wb+bb; idx = argmin_c ||e8c||^2 - 2 e8c.c + ||c||^2
// ---------------------------------------------------------------------------
__global__ __launch_bounds__(256)
void e8_head(const float* __restrict__ y,
             const float* __restrict__ wa, const float* __restrict__ ba,
             const float* __restrict__ wb, const float* __restrict__ bb,
             const float* __restrict__ cb,
             float* __restrict__ codes_out, float* __restrict__ idx_out)
{
    __shared__ float yS[32][256];
    __shared__ float cbS[NCODE * 8];
    __shared__ float cnS[NCODE];
    const int tid = threadIdx.x;
    const int w = tid >> 6, j = tid & 63;
    const int tok0 = blockIdx.x * 32;

    for (int e = tid; e < 32 * 256; e += 256)
        yS[e >> 8][e & 255] = y[(size_t)tok0 * 256 + e];
    for (int e = tid; e < NCODE * 8; e += 256)
        cbS[e] = cb[e];
    __syncthreads();
    for (int e = tid; e < NCODE; e += 256) {
        float s = 0.f;
        #pragma unroll
        for (int q = 0; q < 8; ++q) s = fmaf(cbS[e * 8 + q], cbS[e * 8 + q], s);
        cnS[e] = s;
    }
    __syncthreads();

    float f1[8];
    #pragma unroll
    for (int m = 0; m < 8; ++m) f1[m] = ba[j];
    const int mt0 = w * 8;
    for (int k = 0; k < 256; ++k) {
        float wv = wa[k * 64 + j];
        #pragma unroll
        for (int m = 0; m < 8; ++m)
            f1[m] = fmaf(yS[mt0 + m][k], wv, f1[m]);
    }
    for (int m = 0; m < 8; ++m) {
        float g = geluf_(f1[m]);
        float c8 = (j < 8) ? bb[j] : 0.f;
        for (int k = 0; k < 64; ++k) {
            float gk = __shfl(g, k, 64);
            if (j < 8) c8 = fmaf(gk, wb[k * 8 + j], c8);
        }
        float ec[8];
        #pragma unroll
        for (int q = 0; q < 8; ++q) ec[q] = __shfl(c8, q, 64);
        float fn = 0.f;
        #pragma unroll
        for (int q = 0; q < 8; ++q) fn = fmaf(ec[q], ec[q], fn);

        float bd = 3.4e38f;
        int bi = 0;
        for (int cc = j; cc < NCODE; cc += 64) {
            float dot = 0.f;
            #pragma unroll
            for (int q = 0; q < 8; ++q) dot = fmaf(ec[q], cbS[cc * 8 + q], dot);
            float d = fn + cnS[cc] - 2.f * dot;
            if (d < bd) { bd = d; bi = cc; }
        }
        #pragma unroll
        for (int off = 1; off < 64; off <<= 1) {
            float od = __shfl_xor(bd, off, 64);
            int   oi = __shfl_xor(bi, off, 64);
            if (od < bd || (od == bd && oi < bi)) { bd = od; bi = oi; }
        }
        int t = tok0 + mt0 + m;
        if (j < 8) codes_out[(size_t)t * 8 + j] = cbS[bi * 8 + j];
        if (j == 0) idx_out[t] = (float)bi;
    }
}

// ---------------------------------------------------------------------------
// Velocity norm: vn[b,t] = ||y[b,t]-y[b,t-1]||, vn[b,0]=0. Wave per token.
// ---------------------------------------------------------------------------
__global__ __launch_bounds__(256)
void vn_kernel(const float* __restrict__ y, float* __restrict__ vn)
{
    const int tid = threadIdx.x;
    const int w = tid >> 6, j = tid & 63;
    const int t = blockIdx.x * 4 + w;
    const int tt = t & (TT - 1);
    const float4* cur = (const float4*)(y + (size_t)t * 256);
    const float4* prv = (const float4*)(y + (size_t)(tt == 0 ? t : t - 1) * 256);
    float4 a = cur[j], b = prv[j];
    float dx = a.x - b.x, dy = a.y - b.y, dz = a.z - b.z, dw = a.w - b.w;
    float ss = dx * dx + dy * dy + dz * dz + dw * dw;
    ss += __shfl_xor(ss, 1, 64);
    ss += __shfl_xor(ss, 2, 64);
    ss += __shfl_xor(ss, 4, 64);
    ss += __shfl_xor(ss, 8, 64);
    ss += __shfl_xor(ss, 16, 64);
    ss += __shfl_xor(ss, 32, 64);
    if (j == 0) vn[t] = sqrtf(ss);
}

__global__ __launch_bounds__(256)
void combined_kernel(const float* __restrict__ risk, const float* __restrict__ vn,
                     float* __restrict__ bif)
{
    const int t = blockIdx.x * 256 + threadIdx.x;
    const int tt = t & (TT - 1);
    float v = vn[t];
    float a = (tt == 0) ? 0.f : fabsf(v - vn[t - 1]);
    float cmb = 0.5f * risk[t] + 0.3f * sigmoidf_(v) + 0.2f * sigmoidf_(a);
    bif[t] = (cmb > 0.7f) ? 1.f : 0.f;
}

// ---------------------------------------------------------------------------
extern "C" void kernel_launch(void* const* d_in, const int* in_sizes, int n_in,
                              void* d_out, int out_size, void* d_ws, size_t ws_size,
                              hipStream_t stream)
{
    const float* x          = (const float*)d_in[0];
    const float* in_proj_w  = (const float*)d_in[1];
    const float* in_proj_b  = (const float*)d_in[2];
    const float* conv_w     = (const float*)d_in[3];
    const float* conv_b     = (const float*)d_in[4];
    const float* A_log      = (const float*)d_in[5];
    const float* bc_w       = (const float*)d_in[6];
    const float* bc_b       = (const float*)d_in[7];
    const float* dt_w       = (const float*)d_in[8];
    const float* dt_b       = (const float*)d_in[9];
    const float* out_w      = (const float*)d_in[10];
    const float* out_b      = (const float*)d_in[11];
    const float* cat1_w     = (const float*)d_in[12];
    const float* cat1_b     = (const float*)d_in[13];
    const float* cat2_w     = (const float*)d_in[14];
    const float* cat2_b     = (const float*)d_in[15];
    const float* risk_w     = (const float*)d_in[16];
    const float* risk_b     = (const float*)d_in[17];
    const float* e8a_w      = (const float*)d_in[18];
    const float* e8a_b      = (const float*)d_in[19];
    const float* e8b_w      = (const float*)d_in[20];
    const float* e8b_b      = (const float*)d_in[21];
    const float* codebook   = (const float*)d_in[22];

    float* out = (float*)d_out;
    float* y_out     = out;                        // [B,T,256]
    float* codes_out = out + (size_t)MTOK * 256;   // [B,T,8]
    float* idx_out   = codes_out + (size_t)MTOK * 8;
    float* bif_out   = idx_out + MTOK;

    // ---- workspace: risk/vn up front (used only in head phase), then group
    // buffers. Pick smallest batch-group count G whose footprint fits ws_size.
    float* ws = (float*)d_ws;
    float* risk = ws;
    float* vn   = ws + MTOK;
    float* gbase = ws + 2 * MTOK;

    int G = 8;  // fallback: smallest footprint
    {
        const int cand[4] = {1, 2, 4, 8};
        for (int i = 0; i < 4; ++i) {
            int g = cand[i];
            size_t Mg = (size_t)MTOK / g;
            size_t Bg = BB / g;
            size_t floats = 2 * MTOK                     // risk, vn
                          + Mg * 1024                    // XP (main/dt/yg | gate)
                          + Mg * 512                     // XC
                          + Mg * 32                      // BC
                          + 2 * Bg * SCAN_NC * INNER * SS; // Pbuf, Hbuf
            if (floats * sizeof(float) <= ws_size) { G = g; break; }
        }
    }
    const size_t Mg = (size_t)MTOK / G;
    const int    Bg = BB / G;

    float* XP = gbase;                         // [Mg,1024]
    float* XC = XP + Mg * 1024;                // [Mg,512]
    float* BC = XC + Mg * 512;                 // [Mg,32]
    float* Pb = BC + Mg * 32;                  // [Bg,NC,512,16]
    float* Hb = Pb + (size_t)Bg * SCAN_NC * INNER * SS;

    for (int g = 0; g < G; ++g) {
        const float* xg = x + (size_t)g * Mg * DD;
        float* yg_out   = y_out + (size_t)g * Mg * DD;

        // 1. in_proj: x[Mg,256] @ [256,1024] -> XP (main | gate)
        gemm_bias_act<0><<<dim3(8, Mg / 128), 256, 0, stream>>>(
            xg, 256, in_proj_w, in_proj_b, XP, 1024, 1024, 256);
        // 2. conv: silu(main @ [512,512]) -> XC
        gemm_bias_act<1><<<dim3(4, Mg / 128), 256, 0, stream>>>(
            XP, 1024, conv_w, conv_b, XC, 512, 512, 512);
        // 3. bc: XC @ [512,32] -> BC
        gemm_bias_act<0><<<dim3(1, Mg / 128), 256, 0, stream>>>(
            XC, 512, bc_w, bc_b, BC, 32, 32, 512);
        // 4. dt: softplus(XC @ [512,512]) -> XP cols 0..511 (main is dead)
        gemm_bias_act<2><<<dim3(4, Mg / 128), 256, 0, stream>>>(
            XC, 512, dt_w, dt_b, XP, 1024, 512, 512);
        // 5-7. chunked scan; pass3 writes gated y into XP cols 0..511
        scan_pass1<<<Bg * SCAN_NC * 32, 256, 0, stream>>>(XP, XC, BC, A_log, Pb, Hb);
        scan_pass2<<<Bg * 32, 256, 0, stream>>>(Pb, Hb);
        scan_pass3<<<Bg * SCAN_NC * 32, 256, 0, stream>>>(XP, XC, BC, A_log, Hb);
        // 8. out_proj: yg @ [512,256] -> y (directly into d_out)
        gemm_bias_act<0><<<dim3(2, Mg / 128), 256, 0, stream>>>(
            XP, 1024, out_w, out_b, yg_out, 256, 256, 512);
    }

    // ---- heads on the full y ----
    cat_head<<<MTOK / 32, 256, 0, stream>>>(y_out, cat1_w, cat1_b, cat2_w, cat2_b,
                                            risk_w, risk_b, risk);
    vn_kernel<<<MTOK / 4, 256, 0, stream>>>(y_out, vn);
    combined_kernel<<<MTOK / 256, 256, 0, stream>>>(risk, vn, bif_out);
    e8_head<<<MTOK / 32, 256, 0, stream>>>(y_out, e8a_w, e8a_b, e8b_w, e8b_b,
                                           codebook, codes_out, idx_out);
}

// Round 3
// 1224.132 us; speedup vs baseline: 1.7876x; 1.7876x over previous
//
#include <hip/hip_runtime.h>
#include <hip/hip_bf16.h>
#include <math.h>

// Problem dims
#define BB 8
#define TT 4096
#define DD 256
#define INNER 512
#define SS 16
#define MTOK (BB*TT)          // 32768 tokens
#define NCODE 240

#define SCAN_NC 64
#define SCAN_L  64            // TT / SCAN_NC

typedef unsigned short u16;
typedef unsigned int   u32;
typedef __attribute__((ext_vector_type(8))) short short8;   // 8 bf16 (4 VGPRs)
typedef __attribute__((ext_vector_type(4))) float f32x4;    // 4 fp32 acc

__device__ __forceinline__ float sigmoidf_(float x) { return 1.f / (1.f + expf(-x)); }
__device__ __forceinline__ float siluf_(float x)    { return x / (1.f + expf(-x)); }
__device__ __forceinline__ float geluf_(float x) {
    float x3 = x * x * x;
    return 0.5f * x * (1.f + tanhf(0.7978845608028654f * (x + 0.044715f * x3)));
}
__device__ __forceinline__ float softplusf_(float x) {
    return fmaxf(x, 0.f) + log1pf(expf(-fabsf(x)));
}

// bf16 round-to-nearest-even helpers
__device__ __forceinline__ u16 f2bf(float v) {
    u32 u = __float_as_uint(v);
    u32 r = (u + 0x7FFFu + ((u >> 16) & 1u)) >> 16;
    return (u16)r;
}
__device__ __forceinline__ float bf2f(u16 h) {
    return __uint_as_float(((u32)h) << 16);
}

__device__ __forceinline__ void gload16(const void* g, void* l) {
    __builtin_amdgcn_global_load_lds((const __attribute__((address_space(1))) u32*)g,
                                     (__attribute__((address_space(3))) u32*)l, 16, 0, 0);
}

// ---------------------------------------------------------------------------
// Split-bf16 MFMA GEMM: C[M,N] = act(A[M,K] @ W[K,N] + bias)
// A given as hi/lo bf16 planes [M,K]; W as hi/lo TRANSPOSED planes [Npad,K].
// 3-product split: Ah*Bh + Ah*Bl + Al*Bh (f32-grade precision).
// 128x128 tile, BK=32, 256 thr = 4 waves, wave -> 64x64 quadrant, 4x4 frags.
// LDS tiles [128][32] bf16, XOR-swizzled (chunk ^= (row>>1)&3) both sides.
// ---------------------------------------------------------------------------
template<int MODE>  // 0=in_proj 1=conv(silu->planes) 2=dt(softplus) 3=bc 4=out
__global__ __launch_bounds__(256)
void gemmS(const u16* __restrict__ Ah, const u16* __restrict__ Al, int K,
           const u16* __restrict__ BTh, const u16* __restrict__ BTl,
           const float* __restrict__ bias, int Nstore,
           float* __restrict__ out0, u16* __restrict__ oh, u16* __restrict__ ol)
{
    __shared__ u16 sm[4][128 * 32];   // Ah, Al, Bh, Bl tiles: 8KB each

    const int tid  = threadIdx.x;
    const int lane = tid & 63;
    const int wv   = tid >> 6;
    const int wr   = wv >> 1;          // 0..1
    const int wc   = wv & 1;           // 0..1
    const int lc   = lane & 15;
    const int kc   = lane >> 4;        // 0..3 (k-chunk of 8)
    const int row0 = blockIdx.y * 128;
    const int col0 = blockIdx.x * 128;

    const u16* Agh = Ah + (size_t)row0 * K;
    const u16* Agl = Al + (size_t)row0 * K;
    const u16* Bgh = BTh + (size_t)col0 * K;
    const u16* Bgl = BTl + (size_t)col0 * K;

    f32x4 acc[4][4];
    #pragma unroll
    for (int m = 0; m < 4; ++m)
        #pragma unroll
        for (int n = 0; n < 4; ++n) acc[m][n] = (f32x4)0.f;

    for (int k0 = 0; k0 < K; k0 += 32) {
        // stage 4 planes, swizzled global source -> linear LDS
        #pragma unroll
        for (int c = 0; c < 2; ++c) {
            int e = c * 256 + tid;
            int row = e >> 2, ch = e & 3;
            int chs = ch ^ ((row >> 1) & 3);
            size_t go = (size_t)row * K + k0 + chs * 8;
            gload16(Agh + go, &sm[0][e * 8]);
            gload16(Agl + go, &sm[1][e * 8]);
            gload16(Bgh + go, &sm[2][e * 8]);
            gload16(Bgl + go, &sm[3][e * 8]);
        }
        __syncthreads();

        short8 ah[4], al[4], bh[4], bl[4];
        #pragma unroll
        for (int m = 0; m < 4; ++m) {
            int row = wr * 64 + m * 16 + lc;
            int off = row * 32 + ((kc ^ ((row >> 1) & 3)) << 3);
            ah[m] = *(const short8*)&sm[0][off];
            al[m] = *(const short8*)&sm[1][off];
        }
        #pragma unroll
        for (int n = 0; n < 4; ++n) {
            int row = wc * 64 + n * 16 + lc;
            int off = row * 32 + ((kc ^ ((row >> 1) & 3)) << 3);
            bh[n] = *(const short8*)&sm[2][off];
            bl[n] = *(const short8*)&sm[3][off];
        }
        #pragma unroll
        for (int m = 0; m < 4; ++m)
            #pragma unroll
            for (int n = 0; n < 4; ++n) {
                acc[m][n] = __builtin_amdgcn_mfma_f32_16x16x32_bf16(ah[m], bh[n], acc[m][n], 0, 0, 0);
                acc[m][n] = __builtin_amdgcn_mfma_f32_16x16x32_bf16(ah[m], bl[n], acc[m][n], 0, 0, 0);
                acc[m][n] = __builtin_amdgcn_mfma_f32_16x16x32_bf16(al[m], bh[n], acc[m][n], 0, 0, 0);
            }
        __syncthreads();
    }

    // epilogue: C/D frag layout col=lane&15, row=(lane>>4)*4+reg
    #pragma unroll
    for (int n = 0; n < 4; ++n) {
        int colg = col0 + wc * 64 + n * 16 + lc;
        float bv = (MODE == 3) ? ((colg < Nstore) ? bias[colg] : 0.f) : bias[colg];
        #pragma unroll
        for (int m = 0; m < 4; ++m) {
            f32x4 a = acc[m][n];
            #pragma unroll
            for (int r = 0; r < 4; ++r) {
                int rowg = row0 + wr * 64 + m * 16 + kc * 4 + r;
                float v = a[r] + bv;
                if (MODE == 0) {
                    if (colg < 512) {
                        u16 hh = f2bf(v);
                        oh[(size_t)rowg * 512 + colg] = hh;
                        ol[(size_t)rowg * 512 + colg] = f2bf(v - bf2f(hh));
                    } else {
                        out0[(size_t)rowg * 512 + colg - 512] = v;   // gate f32
                    }
                } else if (MODE == 1) {
                    v = siluf_(v);
                    u16 hh = f2bf(v);
                    oh[(size_t)rowg * 512 + colg] = hh;
                    ol[(size_t)rowg * 512 + colg] = f2bf(v - bf2f(hh));
                } else if (MODE == 2) {
                    out0[(size_t)rowg * 512 + colg] = softplusf_(v);
                } else if (MODE == 3) {
                    if (colg < Nstore) out0[(size_t)rowg * 32 + colg] = v;
                } else {
                    out0[(size_t)rowg * 256 + colg] = v;
                }
            }
        }
    }
}

// ---------------------------------------------------------------------------
// Conversion kernels
// ---------------------------------------------------------------------------
__global__ __launch_bounds__(256)
void split_kernel(const float* __restrict__ s, u16* __restrict__ h,
                  u16* __restrict__ l, int n)
{
    int i = blockIdx.x * 256 + threadIdx.x;
    if (i >= n) return;
    float v = s[i];
    u16 hh = f2bf(v);
    h[i] = hh;
    l[i] = f2bf(v - bf2f(hh));
}

// w [K,N] f32 -> hT/lT [Npad,K] bf16 (zero pad cols >= N)
__global__ __launch_bounds__(256)
void splitT_kernel(const float* __restrict__ w, u16* __restrict__ hT,
                   u16* __restrict__ lT, int K, int N, int Npad)
{
    int idx = blockIdx.x * 256 + threadIdx.x;
    if (idx >= Npad * K) return;
    int n = idx / K, k = idx - n * K;
    float v = (n < N) ? w[(size_t)k * N + n] : 0.f;
    u16 hh = f2bf(v);
    hT[idx] = hh;
    lT[idx] = f2bf(v - bf2f(hh));
}

// ---------------------------------------------------------------------------
// Selective scan, chunked. Block = 256 threads = 16 channels x 16 states.
// ---------------------------------------------------------------------------
__global__ __launch_bounds__(256)
void scan_pass1(const float* __restrict__ DT, const u16* __restrict__ XCh,
                const u16* __restrict__ XCl, const float* __restrict__ BC,
                const float* __restrict__ A_log,
                float* __restrict__ Pbuf, float* __restrict__ Hbuf)
{
    __shared__ float dtS[SCAN_L][16], xS[SCAN_L][16], BS[SCAN_L][16];
    const int bid = blockIdx.x;
    const int dblk = bid & 31;
    const int c = (bid >> 5) & 63;
    const int b = bid >> 11;
    const int d0 = dblk * 16;
    const int tid = threadIdx.x;
    const int row0 = b * TT + c * SCAN_L;

    for (int e = tid; e < SCAN_L * 16; e += 256) {
        int t = e >> 4, j = e & 15;
        size_t r = (size_t)(row0 + t);
        dtS[t][j] = DT[r * 512 + d0 + j];
        xS[t][j]  = bf2f(XCh[r * 512 + d0 + j]) + bf2f(XCl[r * 512 + d0 + j]);
        BS[t][j]  = BC[r * 32 + j];
    }
    __syncthreads();

    const int ch = tid >> 4;
    const int s  = tid & 15;
    const float Aval = -expf(A_log[(d0 + ch) * SS + s]);
    float h = 0.f, p = 1.f;
    #pragma unroll 4
    for (int t = 0; t < SCAN_L; ++t) {
        float dtv = dtS[t][ch];
        float a = expf(dtv * Aval);
        float u = dtv * BS[t][s] * xS[t][ch];
        h = fmaf(a, h, u);
        p *= a;
    }
    size_t o = ((size_t)(b * SCAN_NC + c) * INNER + d0) * SS + tid;
    Pbuf[o] = p;
    Hbuf[o] = h;
}

__global__ __launch_bounds__(256)
void scan_pass2(const float* __restrict__ Pbuf, float* __restrict__ Hbuf)
{
    const int idx = blockIdx.x * 256 + threadIdx.x;
    const int b = idx >> 13;
    const int ds = idx & 8191;
    float hin = 0.f;
    for (int c = 0; c < SCAN_NC; ++c) {
        size_t o = ((size_t)(b * SCAN_NC + c)) * (INNER * SS) + ds;
        float p = Pbuf[o], hh = Hbuf[o];
        Hbuf[o] = hin;
        hin = fmaf(p, hin, hh);
    }
}

// pass3: replay with correct h_in; emit gated y as bf16 hi/lo planes.
__global__ __launch_bounds__(256)
void scan_pass3(const float* __restrict__ DT, const u16* __restrict__ XCh,
                const u16* __restrict__ XCl, const float* __restrict__ BC,
                const float* __restrict__ A_log, const float* __restrict__ GATE,
                const float* __restrict__ Hin,
                u16* __restrict__ YGh, u16* __restrict__ YGl)
{
    __shared__ float dtS[SCAN_L][16], xS[SCAN_L][16], BS[SCAN_L][16];
    __shared__ float CS[SCAN_L][16], GS[SCAN_L][16], ytile[SCAN_L][16];
    const int bid = blockIdx.x;
    const int dblk = bid & 31;
    const int c = (bid >> 5) & 63;
    const int b = bid >> 11;
    const int d0 = dblk * 16;
    const int tid = threadIdx.x;
    const int row0 = b * TT + c * SCAN_L;

    for (int e = tid; e < SCAN_L * 16; e += 256) {
        int t = e >> 4, j = e & 15;
        size_t r = (size_t)(row0 + t);
        dtS[t][j] = DT[r * 512 + d0 + j];
        xS[t][j]  = bf2f(XCh[r * 512 + d0 + j]) + bf2f(XCl[r * 512 + d0 + j]);
        BS[t][j]  = BC[r * 32 + j];
        CS[t][j]  = BC[r * 32 + 16 + j];
        GS[t][j]  = GATE[r * 512 + d0 + j];
    }
    __syncthreads();

    const int ch = tid >> 4;
    const int s  = tid & 15;
    const float Aval = -expf(A_log[(d0 + ch) * SS + s]);
    size_t o = ((size_t)(b * SCAN_NC + c) * INNER + d0) * SS + tid;
    float h = Hin[o];
    #pragma unroll 4
    for (int t = 0; t < SCAN_L; ++t) {
        float dtv = dtS[t][ch];
        float a = expf(dtv * Aval);
        float u = dtv * BS[t][s] * xS[t][ch];
        h = fmaf(a, h, u);
        float yv = h * CS[t][s];
        yv += __shfl_xor(yv, 1, 16);
        yv += __shfl_xor(yv, 2, 16);
        yv += __shfl_xor(yv, 4, 16);
        yv += __shfl_xor(yv, 8, 16);
        if (s == 0) ytile[t][ch] = yv;
    }
    __syncthreads();
    for (int e = tid; e < SCAN_L * 16; e += 256) {
        int t = e >> 4, j = e & 15;
        size_t r = (size_t)(row0 + t);
        float v = ytile[t][j] * siluf_(GS[t][j]);
        u16 hh = f2bf(v);
        YGh[r * 512 + d0 + j] = hh;
        YGl[r * 512 + d0 + j] = f2bf(v - bf2f(hh));
    }
}

// ---------------------------------------------------------------------------
// Heads (unchanged from round 2)
// ---------------------------------------------------------------------------
__global__ __launch_bounds__(256)
void cat_head(const float* __restrict__ y,
              const float* __restrict__ w1, const float* __restrict__ b1,
              const float* __restrict__ w2, const float* __restrict__ b2,
              const float* __restrict__ w3, const float* __restrict__ b3,
              float* __restrict__ risk)
{
    __shared__ float yS[32][256];
    const int tid = threadIdx.x;
    const int w = tid >> 6, j = tid & 63;
    const int tok0 = blockIdx.x * 32;

    for (int e = tid; e < 32 * 256; e += 256)
        yS[e >> 8][e & 255] = y[(size_t)tok0 * 256 + e];
    __syncthreads();

    float f1[8];
    #pragma unroll
    for (int m = 0; m < 8; ++m) f1[m] = b1[j];
    const int mt0 = w * 8;
    for (int k = 0; k < 256; ++k) {
        float wv = w1[k * 64 + j];
        #pragma unroll
        for (int m = 0; m < 8; ++m)
            f1[m] = fmaf(yS[mt0 + m][k], wv, f1[m]);
    }
    for (int m = 0; m < 8; ++m) {
        float g = geluf_(f1[m]);
        float f2 = (j < 32) ? b2[j] : 0.f;
        for (int k = 0; k < 64; ++k) {
            float gk = __shfl(g, k, 64);
            if (j < 32) f2 = fmaf(gk, w2[k * 32 + j], f2);
        }
        float v = (j < 32) ? f2 * w3[j] : 0.f;
        v += __shfl_xor(v, 1, 64);
        v += __shfl_xor(v, 2, 64);
        v += __shfl_xor(v, 4, 64);
        v += __shfl_xor(v, 8, 64);
        v += __shfl_xor(v, 16, 64);
        v += __shfl_xor(v, 32, 64);
        if (j == 0) risk[tok0 + mt0 + m] = sigmoidf_(v + b3[0]);
    }
}

__global__ __launch_bounds__(256)
void e8_head(const float* __restrict__ y,
             const float* __restrict__ wa, const float* __restrict__ ba,
             const float* __restrict__ wb, const float* __restrict__ bb,
             const float* __restrict__ cb,
             float* __restrict__ codes_out, float* __restrict__ idx_out)
{
    __shared__ float yS[32][256];
    __shared__ float cbS[NCODE * 8];
    __shared__ float cnS[NCODE];
    const int tid = threadIdx.x;
    const int w = tid >> 6, j = tid & 63;
    const int tok0 = blockIdx.x * 32;

    for (int e = tid; e < 32 * 256; e += 256)
        yS[e >> 8][e & 255] = y[(size_t)tok0 * 256 + e];
    for (int e = tid; e < NCODE * 8; e += 256)
        cbS[e] = cb[e];
    __syncthreads();
    for (int e = tid; e < NCODE; e += 256) {
        float s = 0.f;
        #pragma unroll
        for (int q = 0; q < 8; ++q) s = fmaf(cbS[e * 8 + q], cbS[e * 8 + q], s);
        cnS[e] = s;
    }
    __syncthreads();

    float f1[8];
    #pragma unroll
    for (int m = 0; m < 8; ++m) f1[m] = ba[j];
    const int mt0 = w * 8;
    for (int k = 0; k < 256; ++k) {
        float wv = wa[k * 64 + j];
        #pragma unroll
        for (int m = 0; m < 8; ++m)
            f1[m] = fmaf(yS[mt0 + m][k], wv, f1[m]);
    }
    for (int m = 0; m < 8; ++m) {
        float g = geluf_(f1[m]);
        float c8 = (j < 8) ? bb[j] : 0.f;
        for (int k = 0; k < 64; ++k) {
            float gk = __shfl(g, k, 64);
            if (j < 8) c8 = fmaf(gk, wb[k * 8 + j], c8);
        }
        float ec[8];
        #pragma unroll
        for (int q = 0; q < 8; ++q) ec[q] = __shfl(c8, q, 64);
        float fn = 0.f;
        #pragma unroll
        for (int q = 0; q < 8; ++q) fn = fmaf(ec[q], ec[q], fn);

        float bd = 3.4e38f;
        int bi = 0;
        for (int cc = j; cc < NCODE; cc += 64) {
            float dot = 0.f;
            #pragma unroll
            for (int q = 0; q < 8; ++q) dot = fmaf(ec[q], cbS[cc * 8 + q], dot);
            float d = fn + cnS[cc] - 2.f * dot;
            if (d < bd) { bd = d; bi = cc; }
        }
        #pragma unroll
        for (int off = 1; off < 64; off <<= 1) {
            float od = __shfl_xor(bd, off, 64);
            int   oi = __shfl_xor(bi, off, 64);
            if (od < bd || (od == bd && oi < bi)) { bd = od; bi = oi; }
        }
        int t = tok0 + mt0 + m;
        if (j < 8) codes_out[(size_t)t * 8 + j] = cbS[bi * 8 + j];
        if (j == 0) idx_out[t] = (float)bi;
    }
}

__global__ __launch_bounds__(256)
void vn_kernel(const float* __restrict__ y, float* __restrict__ vn)
{
    const int tid = threadIdx.x;
    const int w = tid >> 6, j = tid & 63;
    const int t = blockIdx.x * 4 + w;
    const int tt = t & (TT - 1);
    const float4* cur = (const float4*)(y + (size_t)t * 256);
    const float4* prv = (const float4*)(y + (size_t)(tt == 0 ? t : t - 1) * 256);
    float4 a = cur[j], b = prv[j];
    float dx = a.x - b.x, dy = a.y - b.y, dz = a.z - b.z, dw = a.w - b.w;
    float ss = dx * dx + dy * dy + dz * dz + dw * dw;
    ss += __shfl_xor(ss, 1, 64);
    ss += __shfl_xor(ss, 2, 64);
    ss += __shfl_xor(ss, 4, 64);
    ss += __shfl_xor(ss, 8, 64);
    ss += __shfl_xor(ss, 16, 64);
    ss += __shfl_xor(ss, 32, 64);
    if (j == 0) vn[t] = sqrtf(ss);
}

__global__ __launch_bounds__(256)
void combined_kernel(const float* __restrict__ risk, const float* __restrict__ vn,
                     float* __restrict__ bif)
{
    const int t = blockIdx.x * 256 + threadIdx.x;
    const int tt = t & (TT - 1);
    float v = vn[t];
    float a = (tt == 0) ? 0.f : fabsf(v - vn[t - 1]);
    float cmb = 0.5f * risk[t] + 0.3f * sigmoidf_(v) + 0.2f * sigmoidf_(a);
    bif[t] = (cmb > 0.7f) ? 1.f : 0.f;
}

// ---------------------------------------------------------------------------
extern "C" void kernel_launch(void* const* d_in, const int* in_sizes, int n_in,
                              void* d_out, int out_size, void* d_ws, size_t ws_size,
                              hipStream_t stream)
{
    const float* x          = (const float*)d_in[0];
    const float* in_proj_w  = (const float*)d_in[1];
    const float* in_proj_b  = (const float*)d_in[2];
    const float* conv_w     = (const float*)d_in[3];
    const float* conv_b     = (const float*)d_in[4];
    const float* A_log      = (const float*)d_in[5];
    const float* bc_w       = (const float*)d_in[6];
    const float* bc_b       = (const float*)d_in[7];
    const float* dt_w       = (const float*)d_in[8];
    const float* dt_b       = (const float*)d_in[9];
    const float* out_w      = (const float*)d_in[10];
    const float* out_b      = (const float*)d_in[11];
    const float* cat1_w     = (const float*)d_in[12];
    const float* cat1_b     = (const float*)d_in[13];
    const float* cat2_w     = (const float*)d_in[14];
    const float* cat2_b     = (const float*)d_in[15];
    const float* risk_w     = (const float*)d_in[16];
    const float* risk_b     = (const float*)d_in[17];
    const float* e8a_w      = (const float*)d_in[18];
    const float* e8a_b      = (const float*)d_in[19];
    const float* e8b_w      = (const float*)d_in[20];
    const float* e8b_b      = (const float*)d_in[21];
    const float* codebook   = (const float*)d_in[22];

    float* out = (float*)d_out;
    float* y_out     = out;                        // [B,T,256]
    float* codes_out = out + (size_t)MTOK * 256;   // [B,T,8]
    float* idx_out   = codes_out + (size_t)MTOK * 8;
    float* bif_out   = idx_out + MTOK;

    // ---- choose batch-group count G (pure function of ws_size) ----
    const size_t AL = 255;
    #define ALN(x) (((x) + AL) & ~AL)
    size_t fixed_b = 2 * ALN((size_t)MTOK * 4)            // risk, vn
                   + 2 * ALN((size_t)MTOK * 256 * 2)      // xh, xl
                   + 2 * ALN((size_t)1024 * 256 * 2)      // in_projT planes
                   + 2 * ALN((size_t)512 * 512 * 2)       // convT
                   + 2 * ALN((size_t)512 * 512 * 2)       // dtT
                   + 2 * ALN((size_t)128 * 512 * 2)       // bcT (padded)
                   + 2 * ALN((size_t)256 * 512 * 2);      // outT
    int G = 8;
    {
        const int cand[4] = {1, 2, 4, 8};
        for (int i = 0; i < 4; ++i) {
            int g = cand[i];
            size_t Mg = (size_t)MTOK / g, Bg = BB / g;
            size_t grp = 2 * ALN(Mg * 512 * 2)            // MAIN/YG planes
                       + ALN(Mg * 512 * 4)                // GATE
                       + 2 * ALN(Mg * 512 * 2)            // XC planes
                       + ALN(Mg * 512 * 4)                // DT
                       + ALN(Mg * 32 * 4)                 // BC
                       + 2 * ALN(Bg * SCAN_NC * INNER * SS * 4); // P,H
            if (fixed_b + grp <= ws_size) { G = g; break; }
        }
    }
    const size_t Mg = (size_t)MTOK / G;
    const int    Bg = BB / G;

    char* p = (char*)d_ws;
    #define TAKE(T, name, bytes) T* name = (T*)p; p += ALN((size_t)(bytes));
    TAKE(float, risk, MTOK * 4)
    TAKE(float, vn,   MTOK * 4)
    TAKE(u16, xh, (size_t)MTOK * 256 * 2)
    TAKE(u16, xl, (size_t)MTOK * 256 * 2)
    TAKE(u16, wiTh, (size_t)1024 * 256 * 2)
    TAKE(u16, wiTl, (size_t)1024 * 256 * 2)
    TAKE(u16, wcTh, (size_t)512 * 512 * 2)
    TAKE(u16, wcTl, (size_t)512 * 512 * 2)
    TAKE(u16, wdTh, (size_t)512 * 512 * 2)
    TAKE(u16, wdTl, (size_t)512 * 512 * 2)
    TAKE(u16, wbTh, (size_t)128 * 512 * 2)
    TAKE(u16, wbTl, (size_t)128 * 512 * 2)
    TAKE(u16, woTh, (size_t)256 * 512 * 2)
    TAKE(u16, woTl, (size_t)256 * 512 * 2)
    TAKE(u16, MAINh, Mg * 512 * 2)        // also YGh after scan
    TAKE(u16, MAINl, Mg * 512 * 2)        // also YGl
    TAKE(float, GATE, Mg * 512 * 4)
    TAKE(u16, XCh, Mg * 512 * 2)
    TAKE(u16, XCl, Mg * 512 * 2)
    TAKE(float, DT, Mg * 512 * 4)
    TAKE(float, BC, Mg * 32 * 4)
    TAKE(float, Pb, (size_t)Bg * SCAN_NC * INNER * SS * 4)
    TAKE(float, Hb, (size_t)Bg * SCAN_NC * INNER * SS * 4)

    // ---- one-time conversions ----
    split_kernel<<<(MTOK * 256 + 255) / 256, 256, 0, stream>>>(x, xh, xl, MTOK * 256);
    splitT_kernel<<<(1024 * 256 + 255) / 256, 256, 0, stream>>>(in_proj_w, wiTh, wiTl, 256, 1024, 1024);
    splitT_kernel<<<(512 * 512 + 255) / 256, 256, 0, stream>>>(conv_w, wcTh, wcTl, 512, 512, 512);
    splitT_kernel<<<(512 * 512 + 255) / 256, 256, 0, stream>>>(dt_w, wdTh, wdTl, 512, 512, 512);
    splitT_kernel<<<(128 * 512 + 255) / 256, 256, 0, stream>>>(bc_w, wbTh, wbTl, 512, 32, 128);
    splitT_kernel<<<(256 * 512 + 255) / 256, 256, 0, stream>>>(out_w, woTh, woTl, 512, 256, 256);

    for (int g = 0; g < G; ++g) {
        const u16* xgh = xh + (size_t)g * Mg * 256;
        const u16* xgl = xl + (size_t)g * Mg * 256;
        float* yg_out  = y_out + (size_t)g * Mg * 256;

        // 1. in_proj -> MAIN planes (cols 0-511) + GATE f32 (cols 512-1023)
        gemmS<0><<<dim3(8, Mg / 128), 256, 0, stream>>>(
            xgh, xgl, 256, wiTh, wiTl, in_proj_b, 1024, GATE, MAINh, MAINl);
        // 2. conv: silu -> XC planes
        gemmS<1><<<dim3(4, Mg / 128), 256, 0, stream>>>(
            MAINh, MAINl, 512, wcTh, wcTl, conv_b, 512, nullptr, XCh, XCl);
        // 3. dt: softplus -> DT f32
        gemmS<2><<<dim3(4, Mg / 128), 256, 0, stream>>>(
            XCh, XCl, 512, wdTh, wdTl, dt_b, 512, DT, nullptr, nullptr);
        // 4. bc -> BC f32 [Mg,32]
        gemmS<3><<<dim3(1, Mg / 128), 256, 0, stream>>>(
            XCh, XCl, 512, wbTh, wbTl, bc_b, 32, BC, nullptr, nullptr);
        // 5-7. chunked scan; pass3 emits YG planes into MAIN buffers
        scan_pass1<<<Bg * SCAN_NC * 32, 256, 0, stream>>>(DT, XCh, XCl, BC, A_log, Pb, Hb);
        scan_pass2<<<Bg * 32, 256, 0, stream>>>(Pb, Hb);
        scan_pass3<<<Bg * SCAN_NC * 32, 256, 0, stream>>>(DT, XCh, XCl, BC, A_log, GATE,
                                                          Hb, MAINh, MAINl);
        // 8. out_proj -> y f32 (d_out)
        gemmS<4><<<dim3(2, Mg / 128), 256, 0, stream>>>(
            MAINh, MAINl, 512, woTh, woTl, out_b, 256, yg_out, nullptr, nullptr);
    }

    // ---- heads on full y ----
    cat_head<<<MTOK / 32, 256, 0, stream>>>(y_out, cat1_w, cat1_b, cat2_w, cat2_b,
                                            risk_w, risk_b, risk);
    vn_kernel<<<MTOK / 4, 256, 0, stream>>>(y_out, vn);
    combined_kernel<<<MTOK / 256, 256, 0, stream>>>(risk, vn, bif_out);
    e8_head<<<MTOK / 32, 256, 0, stream>>>(y_out, e8a_w, e8a_b, e8b_w, e8b_b,
                                           codebook, codes_out, idx_out);
}

// Round 4
// 1010.600 us; speedup vs baseline: 2.1652x; 1.2113x over previous
//
#include <hip/hip_runtime.h>
#include <hip/hip_bf16.h>
#include <math.h>

// Problem dims
#define BB 8
#define TT 4096
#define DD 256
#define INNER 512
#define SS 16
#define MTOK (BB*TT)          // 32768 tokens
#define NCODE 240

#define SCAN_NC 64
#define SCAN_L  64            // TT / SCAN_NC

typedef unsigned short u16;
typedef unsigned int   u32;
typedef __attribute__((ext_vector_type(8))) short short8;   // 8 bf16 (4 VGPRs)
typedef __attribute__((ext_vector_type(4))) float f32x4;    // 4 fp32 acc

__device__ __forceinline__ float sigmoidf_(float x) { return 1.f / (1.f + expf(-x)); }
__device__ __forceinline__ float siluf_(float x)    { return x / (1.f + expf(-x)); }
__device__ __forceinline__ float geluf_(float x) {
    float x3 = x * x * x;
    return 0.5f * x * (1.f + tanhf(0.7978845608028654f * (x + 0.044715f * x3)));
}
__device__ __forceinline__ float softplusf_(float x) {
    return fmaxf(x, 0.f) + log1pf(expf(-fabsf(x)));
}

// bf16 round-to-nearest-even helpers
__device__ __forceinline__ u16 f2bf(float v) {
    u32 u = __float_as_uint(v);
    u32 r = (u + 0x7FFFu + ((u >> 16) & 1u)) >> 16;
    return (u16)r;
}
__device__ __forceinline__ float bf2f(u16 h) {
    return __uint_as_float(((u32)h) << 16);
}

__device__ __forceinline__ void gload16(const void* g, void* l) {
    __builtin_amdgcn_global_load_lds((const __attribute__((address_space(1))) u32*)g,
                                     (__attribute__((address_space(3))) u32*)l, 16, 0, 0);
}

// ---------------------------------------------------------------------------
// Split-bf16 MFMA GEMM (unchanged from round 3)
// ---------------------------------------------------------------------------
template<int MODE>  // 0=in_proj 1=conv(silu->planes) 2=dt(softplus) 3=bc 4=out
__global__ __launch_bounds__(256)
void gemmS(const u16* __restrict__ Ah, const u16* __restrict__ Al, int K,
           const u16* __restrict__ BTh, const u16* __restrict__ BTl,
           const float* __restrict__ bias, int Nstore,
           float* __restrict__ out0, u16* __restrict__ oh, u16* __restrict__ ol)
{
    __shared__ u16 sm[4][128 * 32];   // Ah, Al, Bh, Bl tiles: 8KB each

    const int tid  = threadIdx.x;
    const int lane = tid & 63;
    const int wv   = tid >> 6;
    const int wr   = wv >> 1;          // 0..1
    const int wc   = wv & 1;           // 0..1
    const int lc   = lane & 15;
    const int kc   = lane >> 4;        // 0..3 (k-chunk of 8)
    const int row0 = blockIdx.y * 128;
    const int col0 = blockIdx.x * 128;

    const u16* Agh = Ah + (size_t)row0 * K;
    const u16* Agl = Al + (size_t)row0 * K;
    const u16* Bgh = BTh + (size_t)col0 * K;
    const u16* Bgl = BTl + (size_t)col0 * K;

    f32x4 acc[4][4];
    #pragma unroll
    for (int m = 0; m < 4; ++m)
        #pragma unroll
        for (int n = 0; n < 4; ++n) acc[m][n] = (f32x4)0.f;

    for (int k0 = 0; k0 < K; k0 += 32) {
        #pragma unroll
        for (int c = 0; c < 2; ++c) {
            int e = c * 256 + tid;
            int row = e >> 2, ch = e & 3;
            int chs = ch ^ ((row >> 1) & 3);
            size_t go = (size_t)row * K + k0 + chs * 8;
            gload16(Agh + go, &sm[0][e * 8]);
            gload16(Agl + go, &sm[1][e * 8]);
            gload16(Bgh + go, &sm[2][e * 8]);
            gload16(Bgl + go, &sm[3][e * 8]);
        }
        __syncthreads();

        short8 ah[4], al[4], bh[4], bl[4];
        #pragma unroll
        for (int m = 0; m < 4; ++m) {
            int row = wr * 64 + m * 16 + lc;
            int off = row * 32 + ((kc ^ ((row >> 1) & 3)) << 3);
            ah[m] = *(const short8*)&sm[0][off];
            al[m] = *(const short8*)&sm[1][off];
        }
        #pragma unroll
        for (int n = 0; n < 4; ++n) {
            int row = wc * 64 + n * 16 + lc;
            int off = row * 32 + ((kc ^ ((row >> 1) & 3)) << 3);
            bh[n] = *(const short8*)&sm[2][off];
            bl[n] = *(const short8*)&sm[3][off];
        }
        #pragma unroll
        for (int m = 0; m < 4; ++m)
            #pragma unroll
            for (int n = 0; n < 4; ++n) {
                acc[m][n] = __builtin_amdgcn_mfma_f32_16x16x32_bf16(ah[m], bh[n], acc[m][n], 0, 0, 0);
                acc[m][n] = __builtin_amdgcn_mfma_f32_16x16x32_bf16(ah[m], bl[n], acc[m][n], 0, 0, 0);
                acc[m][n] = __builtin_amdgcn_mfma_f32_16x16x32_bf16(al[m], bh[n], acc[m][n], 0, 0, 0);
            }
        __syncthreads();
    }

    #pragma unroll
    for (int n = 0; n < 4; ++n) {
        int colg = col0 + wc * 64 + n * 16 + lc;
        float bv = (MODE == 3) ? ((colg < Nstore) ? bias[colg] : 0.f) : bias[colg];
        #pragma unroll
        for (int m = 0; m < 4; ++m) {
            f32x4 a = acc[m][n];
            #pragma unroll
            for (int r = 0; r < 4; ++r) {
                int rowg = row0 + wr * 64 + m * 16 + kc * 4 + r;
                float v = a[r] + bv;
                if (MODE == 0) {
                    if (colg < 512) {
                        u16 hh = f2bf(v);
                        oh[(size_t)rowg * 512 + colg] = hh;
                        ol[(size_t)rowg * 512 + colg] = f2bf(v - bf2f(hh));
                    } else {
                        out0[(size_t)rowg * 512 + colg - 512] = v;   // gate f32
                    }
                } else if (MODE == 1) {
                    v = siluf_(v);
                    u16 hh = f2bf(v);
                    oh[(size_t)rowg * 512 + colg] = hh;
                    ol[(size_t)rowg * 512 + colg] = f2bf(v - bf2f(hh));
                } else if (MODE == 2) {
                    out0[(size_t)rowg * 512 + colg] = softplusf_(v);
                } else if (MODE == 3) {
                    if (colg < Nstore) out0[(size_t)rowg * 32 + colg] = v;
                } else {
                    out0[(size_t)rowg * 256 + colg] = v;
                }
            }
        }
    }
}

// ---------------------------------------------------------------------------
// Conversion kernels
// ---------------------------------------------------------------------------
__global__ __launch_bounds__(256)
void split_kernel(const float* __restrict__ s, u16* __restrict__ h,
                  u16* __restrict__ l, int n)
{
    int i = blockIdx.x * 256 + threadIdx.x;
    if (i >= n) return;
    float v = s[i];
    u16 hh = f2bf(v);
    h[i] = hh;
    l[i] = f2bf(v - bf2f(hh));
}

__global__ __launch_bounds__(256)
void splitT_kernel(const float* __restrict__ w, u16* __restrict__ hT,
                   u16* __restrict__ lT, int K, int N, int Npad)
{
    int idx = blockIdx.x * 256 + threadIdx.x;
    if (idx >= Npad * K) return;
    int n = idx / K, k = idx - n * K;
    float v = (n < N) ? w[(size_t)k * N + n] : 0.f;
    u16 hh = f2bf(v);
    hT[idx] = hh;
    lT[idx] = f2bf(v - bf2f(hh));
}

// ---------------------------------------------------------------------------
// Selective scan, register-state design: one thread owns one channel, all 16
// states in registers. No LDS, no shuffles, no barriers. B/C rows are
// wave-uniform -> scalar loads / SGPR operands.
// Grid: Bg * SCAN_NC * 2 blocks of 256 threads (2 channel-halves).
// ---------------------------------------------------------------------------
__global__ __launch_bounds__(256)
void scan_pass1(const float* __restrict__ DT, const u16* __restrict__ XCh,
                const u16* __restrict__ XCl, const float* __restrict__ BC,
                const float* __restrict__ A_log,
                float* __restrict__ Pbuf, float* __restrict__ Hbuf)
{
    const int bid  = blockIdx.x;
    const int half = bid & 1;
    const int c    = (bid >> 1) & (SCAN_NC - 1);
    const int b    = bid >> 7;
    const int ch   = half * 256 + threadIdx.x;
    const int row0 = b * TT + c * SCAN_L;

    float A[16];
    {
        const float4* ar = (const float4*)(A_log + ch * 16);
        #pragma unroll
        for (int q = 0; q < 4; ++q) {
            float4 v = ar[q];
            A[q * 4 + 0] = -__expf(v.x);
            A[q * 4 + 1] = -__expf(v.y);
            A[q * 4 + 2] = -__expf(v.z);
            A[q * 4 + 3] = -__expf(v.w);
        }
    }

    float h[16];
    #pragma unroll
    for (int s = 0; s < 16; ++s) h[s] = 0.f;
    float dtsum = 0.f;

    const float* dtp = DT  + (size_t)row0 * 512 + ch;
    const u16*   xhp = XCh + (size_t)row0 * 512 + ch;
    const u16*   xlp = XCl + (size_t)row0 * 512 + ch;
    const float* bcp = BC  + (size_t)row0 * 32;

    float dv = dtp[0];
    float xv = bf2f(xhp[0]) + bf2f(xlp[0]);
    for (int t = 0; t < SCAN_L; ++t) {
        const int tn = (t + 1 < SCAN_L) ? t + 1 : t;
        float dvn = dtp[(size_t)tn * 512];
        float xvn = bf2f(xhp[(size_t)tn * 512]) + bf2f(xlp[(size_t)tn * 512]);
        const float* br = bcp + (size_t)t * 32;   // wave-uniform row
        float dtx = dv * xv;
        dtsum += dv;
        #pragma unroll
        for (int s = 0; s < 16; ++s) {
            float a = __expf(dv * A[s]);
            h[s] = fmaf(a, h[s], dtx * br[s]);
        }
        dv = dvn; xv = xvn;
    }

    size_t o = ((size_t)(b * SCAN_NC + c) * 512 + ch) * 16;
    #pragma unroll
    for (int s = 0; s < 16; ++s) {
        Pbuf[o + s] = __expf(dtsum * A[s]);
        Hbuf[o + s] = h[s];
    }
}

__global__ __launch_bounds__(256)
void scan_pass2(const float* __restrict__ Pbuf, float* __restrict__ Hbuf)
{
    const int idx = blockIdx.x * 256 + threadIdx.x;   // Bg*8192 threads
    const int b = idx >> 13;
    const int ds = idx & 8191;
    float hin = 0.f;
    for (int c = 0; c < SCAN_NC; ++c) {
        size_t o = ((size_t)(b * SCAN_NC + c)) * (INNER * SS) + ds;
        float p = Pbuf[o], hh = Hbuf[o];
        Hbuf[o] = hin;
        hin = fmaf(p, hin, hh);
    }
}

__global__ __launch_bounds__(256)
void scan_pass3(const float* __restrict__ DT, const u16* __restrict__ XCh,
                const u16* __restrict__ XCl, const float* __restrict__ BC,
                const float* __restrict__ A_log, const float* __restrict__ GATE,
                const float* __restrict__ Hin,
                u16* __restrict__ YGh, u16* __restrict__ YGl)
{
    const int bid  = blockIdx.x;
    const int half = bid & 1;
    const int c    = (bid >> 1) & (SCAN_NC - 1);
    const int b    = bid >> 7;
    const int ch   = half * 256 + threadIdx.x;
    const int row0 = b * TT + c * SCAN_L;

    float A[16];
    {
        const float4* ar = (const float4*)(A_log + ch * 16);
        #pragma unroll
        for (int q = 0; q < 4; ++q) {
            float4 v = ar[q];
            A[q * 4 + 0] = -__expf(v.x);
            A[q * 4 + 1] = -__expf(v.y);
            A[q * 4 + 2] = -__expf(v.z);
            A[q * 4 + 3] = -__expf(v.w);
        }
    }

    float h[16];
    {
        size_t o = ((size_t)(b * SCAN_NC + c) * 512 + ch) * 16;
        const float4* hr = (const float4*)(Hin + o);
        #pragma unroll
        for (int q = 0; q < 4; ++q) {
            float4 v = hr[q];
            h[q * 4 + 0] = v.x; h[q * 4 + 1] = v.y;
            h[q * 4 + 2] = v.z; h[q * 4 + 3] = v.w;
        }
    }

    const float* dtp = DT   + (size_t)row0 * 512 + ch;
    const u16*   xhp = XCh  + (size_t)row0 * 512 + ch;
    const u16*   xlp = XCl  + (size_t)row0 * 512 + ch;
    const float* gtp = GATE + (size_t)row0 * 512 + ch;
    const float* bcp = BC   + (size_t)row0 * 32;
    u16* yhp = YGh + (size_t)row0 * 512 + ch;
    u16* ylp = YGl + (size_t)row0 * 512 + ch;

    float dv = dtp[0];
    float xv = bf2f(xhp[0]) + bf2f(xlp[0]);
    float gv = gtp[0];
    for (int t = 0; t < SCAN_L; ++t) {
        const int tn = (t + 1 < SCAN_L) ? t + 1 : t;
        float dvn = dtp[(size_t)tn * 512];
        float xvn = bf2f(xhp[(size_t)tn * 512]) + bf2f(xlp[(size_t)tn * 512]);
        float gvn = gtp[(size_t)tn * 512];
        const float* br = bcp + (size_t)t * 32;   // wave-uniform row: B=[0..15], C=[16..31]
        float dtx = dv * xv;
        float y = 0.f;
        #pragma unroll
        for (int s = 0; s < 16; ++s) {
            float a = __expf(dv * A[s]);
            h[s] = fmaf(a, h[s], dtx * br[s]);
            y = fmaf(h[s], br[16 + s], y);
        }
        float yg = y * siluf_(gv);
        u16 hh = f2bf(yg);
        yhp[(size_t)t * 512] = hh;
        ylp[(size_t)t * 512] = f2bf(yg - bf2f(hh));
        dv = dvn; xv = xvn; gv = gvn;
    }
}

// ---------------------------------------------------------------------------
// Heads (unchanged)
// ---------------------------------------------------------------------------
__global__ __launch_bounds__(256)
void cat_head(const float* __restrict__ y,
              const float* __restrict__ w1, const float* __restrict__ b1,
              const float* __restrict__ w2, const float* __restrict__ b2,
              const float* __restrict__ w3, const float* __restrict__ b3,
              float* __restrict__ risk)
{
    __shared__ float yS[32][256];
    const int tid = threadIdx.x;
    const int w = tid >> 6, j = tid & 63;
    const int tok0 = blockIdx.x * 32;

    for (int e = tid; e < 32 * 256; e += 256)
        yS[e >> 8][e & 255] = y[(size_t)tok0 * 256 + e];
    __syncthreads();

    float f1[8];
    #pragma unroll
    for (int m = 0; m < 8; ++m) f1[m] = b1[j];
    const int mt0 = w * 8;
    for (int k = 0; k < 256; ++k) {
        float wv = w1[k * 64 + j];
        #pragma unroll
        for (int m = 0; m < 8; ++m)
            f1[m] = fmaf(yS[mt0 + m][k], wv, f1[m]);
    }
    for (int m = 0; m < 8; ++m) {
        float g = geluf_(f1[m]);
        float f2 = (j < 32) ? b2[j] : 0.f;
        for (int k = 0; k < 64; ++k) {
            float gk = __shfl(g, k, 64);
            if (j < 32) f2 = fmaf(gk, w2[k * 32 + j], f2);
        }
        float v = (j < 32) ? f2 * w3[j] : 0.f;
        v += __shfl_xor(v, 1, 64);
        v += __shfl_xor(v, 2, 64);
        v += __shfl_xor(v, 4, 64);
        v += __shfl_xor(v, 8, 64);
        v += __shfl_xor(v, 16, 64);
        v += __shfl_xor(v, 32, 64);
        if (j == 0) risk[tok0 + mt0 + m] = sigmoidf_(v + b3[0]);
    }
}

__global__ __launch_bounds__(256)
void e8_head(const float* __restrict__ y,
             const float* __restrict__ wa, const float* __restrict__ ba,
             const float* __restrict__ wb, const float* __restrict__ bb,
             const float* __restrict__ cb,
             float* __restrict__ codes_out, float* __restrict__ idx_out)
{
    __shared__ float yS[32][256];
    __shared__ float cbS[NCODE * 8];
    __shared__ float cnS[NCODE];
    const int tid = threadIdx.x;
    const int w = tid >> 6, j = tid & 63;
    const int tok0 = blockIdx.x * 32;

    for (int e = tid; e < 32 * 256; e += 256)
        yS[e >> 8][e & 255] = y[(size_t)tok0 * 256 + e];
    for (int e = tid; e < NCODE * 8; e += 256)
        cbS[e] = cb[e];
    __syncthreads();
    for (int e = tid; e < NCODE; e += 256) {
        float s = 0.f;
        #pragma unroll
        for (int q = 0; q < 8; ++q) s = fmaf(cbS[e * 8 + q], cbS[e * 8 + q], s);
        cnS[e] = s;
    }
    __syncthreads();

    float f1[8];
    #pragma unroll
    for (int m = 0; m < 8; ++m) f1[m] = ba[j];
    const int mt0 = w * 8;
    for (int k = 0; k < 256; ++k) {
        float wv = wa[k * 64 + j];
        #pragma unroll
        for (int m = 0; m < 8; ++m)
            f1[m] = fmaf(yS[mt0 + m][k], wv, f1[m]);
    }
    for (int m = 0; m < 8; ++m) {
        float g = geluf_(f1[m]);
        float c8 = (j < 8) ? bb[j] : 0.f;
        for (int k = 0; k < 64; ++k) {
            float gk = __shfl(g, k, 64);
            if (j < 8) c8 = fmaf(gk, wb[k * 8 + j], c8);
        }
        float ec[8];
        #pragma unroll
        for (int q = 0; q < 8; ++q) ec[q] = __shfl(c8, q, 64);
        float fn = 0.f;
        #pragma unroll
        for (int q = 0; q < 8; ++q) fn = fmaf(ec[q], ec[q], fn);

        float bd = 3.4e38f;
        int bi = 0;
        for (int cc = j; cc < NCODE; cc += 64) {
            float dot = 0.f;
            #pragma unroll
            for (int q = 0; q < 8; ++q) dot = fmaf(ec[q], cbS[cc * 8 + q], dot);
            float d = fn + cnS[cc] - 2.f * dot;
            if (d < bd) { bd = d; bi = cc; }
        }
        #pragma unroll
        for (int off = 1; off < 64; off <<= 1) {
            float od = __shfl_xor(bd, off, 64);
            int   oi = __shfl_xor(bi, off, 64);
            if (od < bd || (od == bd && oi < bi)) { bd = od; bi = oi; }
        }
        int t = tok0 + mt0 + m;
        if (j < 8) codes_out[(size_t)t * 8 + j] = cbS[bi * 8 + j];
        if (j == 0) idx_out[t] = (float)bi;
    }
}

__global__ __launch_bounds__(256)
void vn_kernel(const float* __restrict__ y, float* __restrict__ vn)
{
    const int tid = threadIdx.x;
    const int w = tid >> 6, j = tid & 63;
    const int t = blockIdx.x * 4 + w;
    const int tt = t & (TT - 1);
    const float4* cur = (const float4*)(y + (size_t)t * 256);
    const float4* prv = (const float4*)(y + (size_t)(tt == 0 ? t : t - 1) * 256);
    float4 a = cur[j], b = prv[j];
    float dx = a.x - b.x, dy = a.y - b.y, dz = a.z - b.z, dw = a.w - b.w;
    float ss = dx * dx + dy * dy + dz * dz + dw * dw;
    ss += __shfl_xor(ss, 1, 64);
    ss += __shfl_xor(ss, 2, 64);
    ss += __shfl_xor(ss, 4, 64);
    ss += __shfl_xor(ss, 8, 64);
    ss += __shfl_xor(ss, 16, 64);
    ss += __shfl_xor(ss, 32, 64);
    if (j == 0) vn[t] = sqrtf(ss);
}

__global__ __launch_bounds__(256)
void combined_kernel(const float* __restrict__ risk, const float* __restrict__ vn,
                     float* __restrict__ bif)
{
    const int t = blockIdx.x * 256 + threadIdx.x;
    const int tt = t & (TT - 1);
    float v = vn[t];
    float a = (tt == 0) ? 0.f : fabsf(v - vn[t - 1]);
    float cmb = 0.5f * risk[t] + 0.3f * sigmoidf_(v) + 0.2f * sigmoidf_(a);
    bif[t] = (cmb > 0.7f) ? 1.f : 0.f;
}

// ---------------------------------------------------------------------------
extern "C" void kernel_launch(void* const* d_in, const int* in_sizes, int n_in,
                              void* d_out, int out_size, void* d_ws, size_t ws_size,
                              hipStream_t stream)
{
    const float* x          = (const float*)d_in[0];
    const float* in_proj_w  = (const float*)d_in[1];
    const float* in_proj_b  = (const float*)d_in[2];
    const float* conv_w     = (const float*)d_in[3];
    const float* conv_b     = (const float*)d_in[4];
    const float* A_log      = (const float*)d_in[5];
    const float* bc_w       = (const float*)d_in[6];
    const float* bc_b       = (const float*)d_in[7];
    const float* dt_w       = (const float*)d_in[8];
    const float* dt_b       = (const float*)d_in[9];
    const float* out_w      = (const float*)d_in[10];
    const float* out_b      = (const float*)d_in[11];
    const float* cat1_w     = (const float*)d_in[12];
    const float* cat1_b     = (const float*)d_in[13];
    const float* cat2_w     = (const float*)d_in[14];
    const float* cat2_b     = (const float*)d_in[15];
    const float* risk_w     = (const float*)d_in[16];
    const float* risk_b     = (const float*)d_in[17];
    const float* e8a_w      = (const float*)d_in[18];
    const float* e8a_b      = (const float*)d_in[19];
    const float* e8b_w      = (const float*)d_in[20];
    const float* e8b_b      = (const float*)d_in[21];
    const float* codebook   = (const float*)d_in[22];

    float* out = (float*)d_out;
    float* y_out     = out;                        // [B,T,256]
    float* codes_out = out + (size_t)MTOK * 256;   // [B,T,8]
    float* idx_out   = codes_out + (size_t)MTOK * 8;
    float* bif_out   = idx_out + MTOK;

    // ---- choose batch-group count G (pure function of ws_size) ----
    const size_t AL = 255;
    #define ALN(x) (((x) + AL) & ~AL)
    size_t fixed_b = 2 * ALN((size_t)MTOK * 4)            // risk, vn
                   + 2 * ALN((size_t)MTOK * 256 * 2)      // xh, xl
                   + 2 * ALN((size_t)1024 * 256 * 2)      // in_projT planes
                   + 2 * ALN((size_t)512 * 512 * 2)       // convT
                   + 2 * ALN((size_t)512 * 512 * 2)       // dtT
                   + 2 * ALN((size_t)128 * 512 * 2)       // bcT (padded)
                   + 2 * ALN((size_t)256 * 512 * 2);      // outT
    int G = 8;
    {
        const int cand[4] = {1, 2, 4, 8};
        for (int i = 0; i < 4; ++i) {
            int g = cand[i];
            size_t Mg = (size_t)MTOK / g, Bg = BB / g;
            size_t grp = 2 * ALN(Mg * 512 * 2)            // MAIN/YG planes
                       + ALN(Mg * 512 * 4)                // GATE
                       + 2 * ALN(Mg * 512 * 2)            // XC planes
                       + ALN(Mg * 512 * 4)                // DT
                       + ALN(Mg * 32 * 4)                 // BC
                       + 2 * ALN(Bg * SCAN_NC * INNER * SS * 4); // P,H
            if (fixed_b + grp <= ws_size) { G = g; break; }
        }
    }
    const size_t Mg = (size_t)MTOK / G;
    const int    Bg = BB / G;

    char* p = (char*)d_ws;
    #define TAKE(T, name, bytes) T* name = (T*)p; p += ALN((size_t)(bytes));
    TAKE(float, risk, MTOK * 4)
    TAKE(float, vn,   MTOK * 4)
    TAKE(u16, xh, (size_t)MTOK * 256 * 2)
    TAKE(u16, xl, (size_t)MTOK * 256 * 2)
    TAKE(u16, wiTh, (size_t)1024 * 256 * 2)
    TAKE(u16, wiTl, (size_t)1024 * 256 * 2)
    TAKE(u16, wcTh, (size_t)512 * 512 * 2)
    TAKE(u16, wcTl, (size_t)512 * 512 * 2)
    TAKE(u16, wdTh, (size_t)512 * 512 * 2)
    TAKE(u16, wdTl, (size_t)512 * 512 * 2)
    TAKE(u16, wbTh, (size_t)128 * 512 * 2)
    TAKE(u16, wbTl, (size_t)128 * 512 * 2)
    TAKE(u16, woTh, (size_t)256 * 512 * 2)
    TAKE(u16, woTl, (size_t)256 * 512 * 2)
    TAKE(u16, MAINh, Mg * 512 * 2)        // also YGh after scan
    TAKE(u16, MAINl, Mg * 512 * 2)        // also YGl
    TAKE(float, GATE, Mg * 512 * 4)
    TAKE(u16, XCh, Mg * 512 * 2)
    TAKE(u16, XCl, Mg * 512 * 2)
    TAKE(float, DT, Mg * 512 * 4)
    TAKE(float, BC, Mg * 32 * 4)
    TAKE(float, Pb, (size_t)Bg * SCAN_NC * INNER * SS * 4)
    TAKE(float, Hb, (size_t)Bg * SCAN_NC * INNER * SS * 4)

    // ---- one-time conversions ----
    split_kernel<<<(MTOK * 256 + 255) / 256, 256, 0, stream>>>(x, xh, xl, MTOK * 256);
    splitT_kernel<<<(1024 * 256 + 255) / 256, 256, 0, stream>>>(in_proj_w, wiTh, wiTl, 256, 1024, 1024);
    splitT_kernel<<<(512 * 512 + 255) / 256, 256, 0, stream>>>(conv_w, wcTh, wcTl, 512, 512, 512);
    splitT_kernel<<<(512 * 512 + 255) / 256, 256, 0, stream>>>(dt_w, wdTh, wdTl, 512, 512, 512);
    splitT_kernel<<<(128 * 512 + 255) / 256, 256, 0, stream>>>(bc_w, wbTh, wbTl, 512, 32, 128);
    splitT_kernel<<<(256 * 512 + 255) / 256, 256, 0, stream>>>(out_w, woTh, woTl, 512, 256, 256);

    for (int g = 0; g < G; ++g) {
        const u16* xgh = xh + (size_t)g * Mg * 256;
        const u16* xgl = xl + (size_t)g * Mg * 256;
        float* yg_out  = y_out + (size_t)g * Mg * 256;

        // 1. in_proj -> MAIN planes (cols 0-511) + GATE f32 (cols 512-1023)
        gemmS<0><<<dim3(8, Mg / 128), 256, 0, stream>>>(
            xgh, xgl, 256, wiTh, wiTl, in_proj_b, 1024, GATE, MAINh, MAINl);
        // 2. conv: silu -> XC planes
        gemmS<1><<<dim3(4, Mg / 128), 256, 0, stream>>>(
            MAINh, MAINl, 512, wcTh, wcTl, conv_b, 512, nullptr, XCh, XCl);
        // 3. dt: softplus -> DT f32
        gemmS<2><<<dim3(4, Mg / 128), 256, 0, stream>>>(
            XCh, XCl, 512, wdTh, wdTl, dt_b, 512, DT, nullptr, nullptr);
        // 4. bc -> BC f32 [Mg,32]
        gemmS<3><<<dim3(1, Mg / 128), 256, 0, stream>>>(
            XCh, XCl, 512, wbTh, wbTl, bc_b, 32, BC, nullptr, nullptr);
        // 5-7. chunked scan (register-state kernels)
        scan_pass1<<<Bg * SCAN_NC * 2, 256, 0, stream>>>(DT, XCh, XCl, BC, A_log, Pb, Hb);
        scan_pass2<<<Bg * 32, 256, 0, stream>>>(Pb, Hb);
        scan_pass3<<<Bg * SCAN_NC * 2, 256, 0, stream>>>(DT, XCh, XCl, BC, A_log, GATE,
                                                         Hb, MAINh, MAINl);
        // 8. out_proj -> y f32 (d_out)
        gemmS<4><<<dim3(2, Mg / 128), 256, 0, stream>>>(
            MAINh, MAINl, 512, woTh, woTl, out_b, 256, yg_out, nullptr, nullptr);
    }

    // ---- heads on full y ----
    cat_head<<<MTOK / 32, 256, 0, stream>>>(y_out, cat1_w, cat1_b, cat2_w, cat2_b,
                                            risk_w, risk_b, risk);
    vn_kernel<<<MTOK / 4, 256, 0, stream>>>(y_out, vn);
    combined_kernel<<<MTOK / 256, 256, 0, stream>>>(risk, vn, bif_out);
    e8_head<<<MTOK / 32, 256, 0, stream>>>(y_out, e8a_w, e8a_b, e8b_w, e8b_b,
                                           codebook, codes_out, idx_out);
}

// Round 5
// 842.971 us; speedup vs baseline: 2.5958x; 1.1989x over previous
//
#include <hip/hip_runtime.h>
#include <hip/hip_bf16.h>
#include <math.h>

// Problem dims
#define BB 8
#define TT 4096
#define DD 256
#define INNER 512
#define SS 16
#define MTOK (BB*TT)          // 32768 tokens
#define NCODE 240

#define SCAN_NC 64
#define SCAN_L  64            // TT / SCAN_NC

typedef unsigned short u16;
typedef unsigned int   u32;
typedef __attribute__((ext_vector_type(8))) short short8;   // 8 bf16 (4 VGPRs)
typedef __attribute__((ext_vector_type(4))) float f32x4;    // 4 fp32 acc

__device__ __forceinline__ float sigmoidf_(float x) { return 1.f / (1.f + expf(-x)); }
__device__ __forceinline__ float siluf_(float x)    { return x / (1.f + expf(-x)); }
__device__ __forceinline__ float geluf_(float x) {
    float x3 = x * x * x;
    return 0.5f * x * (1.f + tanhf(0.7978845608028654f * (x + 0.044715f * x3)));
}
__device__ __forceinline__ float softplusf_(float x) {
    return fmaxf(x, 0.f) + log1pf(expf(-fabsf(x)));
}

// bf16 round-to-nearest-even helpers
__device__ __forceinline__ u16 f2bf(float v) {
    u32 u = __float_as_uint(v);
    u32 r = (u + 0x7FFFu + ((u >> 16) & 1u)) >> 16;
    return (u16)r;
}
__device__ __forceinline__ float bf2f(u16 h) {
    return __uint_as_float(((u32)h) << 16);
}

__device__ __forceinline__ void gload16(const void* g, void* l) {
    __builtin_amdgcn_global_load_lds((const __attribute__((address_space(1))) u32*)g,
                                     (__attribute__((address_space(3))) u32*)l, 16, 0, 0);
}

// ---------------------------------------------------------------------------
// Split-bf16 MFMA GEMM: C[M,N] = act(A[M,K] @ W[K,N] + bias)
// MODE: 0=in_proj 1=conv(silu->planes) 2=dt(softplus) 3=bc 4=out(+planes)
//       5=head (gelu -> f32 [M,128])
// ---------------------------------------------------------------------------
template<int MODE>
__global__ __launch_bounds__(256)
void gemmS(const u16* __restrict__ Ah, const u16* __restrict__ Al, int K,
           const u16* __restrict__ BTh, const u16* __restrict__ BTl,
           const float* __restrict__ bias, int Nstore,
           float* __restrict__ out0, u16* __restrict__ oh, u16* __restrict__ ol)
{
    __shared__ u16 sm[4][128 * 32];   // Ah, Al, Bh, Bl tiles: 8KB each

    const int tid  = threadIdx.x;
    const int lane = tid & 63;
    const int wv   = tid >> 6;
    const int wr   = wv >> 1;          // 0..1
    const int wc   = wv & 1;           // 0..1
    const int lc   = lane & 15;
    const int kc   = lane >> 4;        // 0..3 (k-chunk of 8)
    const int row0 = blockIdx.y * 128;
    const int col0 = blockIdx.x * 128;

    const u16* Agh = Ah + (size_t)row0 * K;
    const u16* Agl = Al + (size_t)row0 * K;
    const u16* Bgh = BTh + (size_t)col0 * K;
    const u16* Bgl = BTl + (size_t)col0 * K;

    f32x4 acc[4][4];
    #pragma unroll
    for (int m = 0; m < 4; ++m)
        #pragma unroll
        for (int n = 0; n < 4; ++n) acc[m][n] = (f32x4)0.f;

    for (int k0 = 0; k0 < K; k0 += 32) {
        #pragma unroll
        for (int c = 0; c < 2; ++c) {
            int e = c * 256 + tid;
            int row = e >> 2, ch = e & 3;
            int chs = ch ^ ((row >> 1) & 3);
            size_t go = (size_t)row * K + k0 + chs * 8;
            gload16(Agh + go, &sm[0][e * 8]);
            gload16(Agl + go, &sm[1][e * 8]);
            gload16(Bgh + go, &sm[2][e * 8]);
            gload16(Bgl + go, &sm[3][e * 8]);
        }
        __syncthreads();

        short8 ah[4], al[4], bh[4], bl[4];
        #pragma unroll
        for (int m = 0; m < 4; ++m) {
            int row = wr * 64 + m * 16 + lc;
            int off = row * 32 + ((kc ^ ((row >> 1) & 3)) << 3);
            ah[m] = *(const short8*)&sm[0][off];
            al[m] = *(const short8*)&sm[1][off];
        }
        #pragma unroll
        for (int n = 0; n < 4; ++n) {
            int row = wc * 64 + n * 16 + lc;
            int off = row * 32 + ((kc ^ ((row >> 1) & 3)) << 3);
            bh[n] = *(const short8*)&sm[2][off];
            bl[n] = *(const short8*)&sm[3][off];
        }
        #pragma unroll
        for (int m = 0; m < 4; ++m)
            #pragma unroll
            for (int n = 0; n < 4; ++n) {
                acc[m][n] = __builtin_amdgcn_mfma_f32_16x16x32_bf16(ah[m], bh[n], acc[m][n], 0, 0, 0);
                acc[m][n] = __builtin_amdgcn_mfma_f32_16x16x32_bf16(ah[m], bl[n], acc[m][n], 0, 0, 0);
                acc[m][n] = __builtin_amdgcn_mfma_f32_16x16x32_bf16(al[m], bh[n], acc[m][n], 0, 0, 0);
            }
        __syncthreads();
    }

    #pragma unroll
    for (int n = 0; n < 4; ++n) {
        int colg = col0 + wc * 64 + n * 16 + lc;
        float bv = (MODE == 3) ? ((colg < Nstore) ? bias[colg] : 0.f) : bias[colg];
        #pragma unroll
        for (int m = 0; m < 4; ++m) {
            f32x4 a = acc[m][n];
            #pragma unroll
            for (int r = 0; r < 4; ++r) {
                int rowg = row0 + wr * 64 + m * 16 + kc * 4 + r;
                float v = a[r] + bv;
                if (MODE == 0) {
                    if (colg < 512) {
                        u16 hh = f2bf(v);
                        oh[(size_t)rowg * 512 + colg] = hh;
                        ol[(size_t)rowg * 512 + colg] = f2bf(v - bf2f(hh));
                    } else {
                        out0[(size_t)rowg * 512 + colg - 512] = v;   // gate f32
                    }
                } else if (MODE == 1) {
                    v = siluf_(v);
                    u16 hh = f2bf(v);
                    oh[(size_t)rowg * 512 + colg] = hh;
                    ol[(size_t)rowg * 512 + colg] = f2bf(v - bf2f(hh));
                } else if (MODE == 2) {
                    out0[(size_t)rowg * 512 + colg] = softplusf_(v);
                } else if (MODE == 3) {
                    if (colg < Nstore) out0[(size_t)rowg * 32 + colg] = v;
                } else if (MODE == 4) {
                    out0[(size_t)rowg * 256 + colg] = v;             // y f32
                    u16 hh = f2bf(v);
                    oh[(size_t)rowg * 256 + colg] = hh;              // y planes
                    ol[(size_t)rowg * 256 + colg] = f2bf(v - bf2f(hh));
                } else {  // MODE 5: head layer-1, gelu
                    out0[(size_t)rowg * 128 + colg] = geluf_(v);
                }
            }
        }
    }
}

// ---------------------------------------------------------------------------
// Conversion kernels
// ---------------------------------------------------------------------------
__global__ __launch_bounds__(256)
void split_kernel(const float* __restrict__ s, u16* __restrict__ h,
                  u16* __restrict__ l, int n)
{
    int i = blockIdx.x * 256 + threadIdx.x;
    if (i >= n) return;
    float v = s[i];
    u16 hh = f2bf(v);
    h[i] = hh;
    l[i] = f2bf(v - bf2f(hh));
}

__global__ __launch_bounds__(256)
void splitT_kernel(const float* __restrict__ w, u16* __restrict__ hT,
                   u16* __restrict__ lT, int K, int N, int Npad)
{
    int idx = blockIdx.x * 256 + threadIdx.x;
    if (idx >= Npad * K) return;
    int n = idx / K, k = idx - n * K;
    float v = (n < N) ? w[(size_t)k * N + n] : 0.f;
    u16 hh = f2bf(v);
    hT[idx] = hh;
    lT[idx] = f2bf(v - bf2f(hh));
}

// concat [cat1_w | e8a_w] -> transposed split planes [128,256] + bias[128]
__global__ __launch_bounds__(256)
void headprep_kernel(const float* __restrict__ c1w, const float* __restrict__ c1b,
                     const float* __restrict__ e8aw, const float* __restrict__ e8ab,
                     u16* __restrict__ hT, u16* __restrict__ lT, float* __restrict__ hb)
{
    int idx = blockIdx.x * 256 + threadIdx.x;
    if (idx < 128) hb[idx] = (idx < 64) ? c1b[idx] : e8ab[idx - 64];
    if (idx >= 128 * 256) return;
    int n = idx >> 8, k = idx & 255;
    float v = (n < 64) ? c1w[(size_t)k * 64 + n] : e8aw[(size_t)k * 64 + (n - 64)];
    u16 hh = f2bf(v);
    hT[idx] = hh;
    lT[idx] = f2bf(v - bf2f(hh));
}

// ---------------------------------------------------------------------------
// Selective scan, register-state design (unchanged from round 4)
// ---------------------------------------------------------------------------
__global__ __launch_bounds__(256)
void scan_pass1(const float* __restrict__ DT, const u16* __restrict__ XCh,
                const u16* __restrict__ XCl, const float* __restrict__ BC,
                const float* __restrict__ A_log,
                float* __restrict__ Pbuf, float* __restrict__ Hbuf)
{
    const int bid  = blockIdx.x;
    const int half = bid & 1;
    const int c    = (bid >> 1) & (SCAN_NC - 1);
    const int b    = bid >> 7;
    const int ch   = half * 256 + threadIdx.x;
    const int row0 = b * TT + c * SCAN_L;

    float A[16];
    {
        const float4* ar = (const float4*)(A_log + ch * 16);
        #pragma unroll
        for (int q = 0; q < 4; ++q) {
            float4 v = ar[q];
            A[q * 4 + 0] = -__expf(v.x);
            A[q * 4 + 1] = -__expf(v.y);
            A[q * 4 + 2] = -__expf(v.z);
            A[q * 4 + 3] = -__expf(v.w);
        }
    }

    float h[16];
    #pragma unroll
    for (int s = 0; s < 16; ++s) h[s] = 0.f;
    float dtsum = 0.f;

    const float* dtp = DT  + (size_t)row0 * 512 + ch;
    const u16*   xhp = XCh + (size_t)row0 * 512 + ch;
    const u16*   xlp = XCl + (size_t)row0 * 512 + ch;
    const float* bcp = BC  + (size_t)row0 * 32;

    float dv = dtp[0];
    float xv = bf2f(xhp[0]) + bf2f(xlp[0]);
    for (int t = 0; t < SCAN_L; ++t) {
        const int tn = (t + 1 < SCAN_L) ? t + 1 : t;
        float dvn = dtp[(size_t)tn * 512];
        float xvn = bf2f(xhp[(size_t)tn * 512]) + bf2f(xlp[(size_t)tn * 512]);
        const float* br = bcp + (size_t)t * 32;   // wave-uniform row
        float dtx = dv * xv;
        dtsum += dv;
        #pragma unroll
        for (int s = 0; s < 16; ++s) {
            float a = __expf(dv * A[s]);
            h[s] = fmaf(a, h[s], dtx * br[s]);
        }
        dv = dvn; xv = xvn;
    }

    size_t o = ((size_t)(b * SCAN_NC + c) * 512 + ch) * 16;
    #pragma unroll
    for (int s = 0; s < 16; ++s) {
        Pbuf[o + s] = __expf(dtsum * A[s]);
        Hbuf[o + s] = h[s];
    }
}

__global__ __launch_bounds__(256)
void scan_pass2(const float* __restrict__ Pbuf, float* __restrict__ Hbuf)
{
    const int idx = blockIdx.x * 256 + threadIdx.x;   // Bg*8192 threads
    const int b = idx >> 13;
    const int ds = idx & 8191;
    float hin = 0.f;
    for (int c = 0; c < SCAN_NC; ++c) {
        size_t o = ((size_t)(b * SCAN_NC + c)) * (INNER * SS) + ds;
        float p = Pbuf[o], hh = Hbuf[o];
        Hbuf[o] = hin;
        hin = fmaf(p, hin, hh);
    }
}

__global__ __launch_bounds__(256)
void scan_pass3(const float* __restrict__ DT, const u16* __restrict__ XCh,
                const u16* __restrict__ XCl, const float* __restrict__ BC,
                const float* __restrict__ A_log, const float* __restrict__ GATE,
                const float* __restrict__ Hin,
                u16* __restrict__ YGh, u16* __restrict__ YGl)
{
    const int bid  = blockIdx.x;
    const int half = bid & 1;
    const int c    = (bid >> 1) & (SCAN_NC - 1);
    const int b    = bid >> 7;
    const int ch   = half * 256 + threadIdx.x;
    const int row0 = b * TT + c * SCAN_L;

    float A[16];
    {
        const float4* ar = (const float4*)(A_log + ch * 16);
        #pragma unroll
        for (int q = 0; q < 4; ++q) {
            float4 v = ar[q];
            A[q * 4 + 0] = -__expf(v.x);
            A[q * 4 + 1] = -__expf(v.y);
            A[q * 4 + 2] = -__expf(v.z);
            A[q * 4 + 3] = -__expf(v.w);
        }
    }

    float h[16];
    {
        size_t o = ((size_t)(b * SCAN_NC + c) * 512 + ch) * 16;
        const float4* hr = (const float4*)(Hin + o);
        #pragma unroll
        for (int q = 0; q < 4; ++q) {
            float4 v = hr[q];
            h[q * 4 + 0] = v.x; h[q * 4 + 1] = v.y;
            h[q * 4 + 2] = v.z; h[q * 4 + 3] = v.w;
        }
    }

    const float* dtp = DT   + (size_t)row0 * 512 + ch;
    const u16*   xhp = XCh  + (size_t)row0 * 512 + ch;
    const u16*   xlp = XCl  + (size_t)row0 * 512 + ch;
    const float* gtp = GATE + (size_t)row0 * 512 + ch;
    const float* bcp = BC   + (size_t)row0 * 32;
    u16* yhp = YGh + (size_t)row0 * 512 + ch;
    u16* ylp = YGl + (size_t)row0 * 512 + ch;

    float dv = dtp[0];
    float xv = bf2f(xhp[0]) + bf2f(xlp[0]);
    float gv = gtp[0];
    for (int t = 0; t < SCAN_L; ++t) {
        const int tn = (t + 1 < SCAN_L) ? t + 1 : t;
        float dvn = dtp[(size_t)tn * 512];
        float xvn = bf2f(xhp[(size_t)tn * 512]) + bf2f(xlp[(size_t)tn * 512]);
        float gvn = gtp[(size_t)tn * 512];
        const float* br = bcp + (size_t)t * 32;   // B=[0..15], C=[16..31]
        float dtx = dv * xv;
        float y = 0.f;
        #pragma unroll
        for (int s = 0; s < 16; ++s) {
            float a = __expf(dv * A[s]);
            h[s] = fmaf(a, h[s], dtx * br[s]);
            y = fmaf(h[s], br[16 + s], y);
        }
        float yg = y * siluf_(gv);
        u16 hh = f2bf(yg);
        yhp[(size_t)t * 512] = hh;
        ylp[(size_t)t * 512] = f2bf(yg - bf2f(hh));
        dv = dvn; xv = xvn; gv = gvn;
    }
}

// ---------------------------------------------------------------------------
// Head finisher: F1[M,128] = gelu(y@[cat1|e8a]+b) already computed.
// Block = 64 tokens, 256 threads = 4 roles/token.
// roles 0,1: f2 = F1c@cat2_w (16 dims each) -> partial risk dot
// roles 2,3: e8c = F1e@e8b_w (redundant) -> 120 codes each -> argmin merge
// ---------------------------------------------------------------------------
__global__ __launch_bounds__(256)
void head_finish(const float* __restrict__ F1,
                 const float* __restrict__ w2, const float* __restrict__ b2,
                 const float* __restrict__ w3, const float* __restrict__ b3,
                 const float* __restrict__ wb, const float* __restrict__ bb,
                 const float* __restrict__ cb,
                 float* __restrict__ risk, float* __restrict__ codes_out,
                 float* __restrict__ idx_out)
{
    __shared__ float F1s[64][129];      // +1 pad: conflict-free row reads
    __shared__ float w2S[64 * 32];
    __shared__ float wbS[64 * 8];
    __shared__ float cbS[NCODE * 8];
    __shared__ float cnS[NCODE];
    __shared__ float w3S[32];
    __shared__ float b2S[32];
    __shared__ float bbS[8];
    const int tid = threadIdx.x;
    const int tok0 = blockIdx.x * 64;

    for (int e = tid; e < 64 * 128; e += 256)
        F1s[e >> 7][e & 127] = F1[(size_t)tok0 * 128 + e];
    for (int e = tid; e < 64 * 32; e += 256) w2S[e] = w2[e];
    for (int e = tid; e < 64 * 8; e += 256) wbS[e] = wb[e];
    for (int e = tid; e < NCODE * 8; e += 256) cbS[e] = cb[e];
    if (tid < 32) { w3S[tid] = w3[tid]; b2S[tid] = b2[tid]; }
    if (tid < 8) bbS[tid] = bb[tid];
    __syncthreads();
    for (int e = tid; e < NCODE; e += 256) {
        float s = 0.f;
        #pragma unroll
        for (int q = 0; q < 8; ++q) s = fmaf(cbS[e * 8 + q], cbS[e * 8 + q], s);
        cnS[e] = s;
    }
    __syncthreads();

    const int lane = tid & 63;
    const int wv   = tid >> 6;
    const int tl   = wv * 16 + (lane >> 2);   // token_local 0..63
    const int role = lane & 3;
    const float* f1c = &F1s[tl][0];
    const float* f1e = &F1s[tl][64];

    float v = 0.f;
    float bd = 3.4e38f;
    int bi = 0;

    if (role < 2) {
        float f2[16];
        #pragma unroll
        for (int d = 0; d < 16; ++d) f2[d] = b2S[role * 16 + d];
        for (int k = 0; k < 64; ++k) {
            float fv = f1c[k];
            #pragma unroll
            for (int d = 0; d < 16; ++d)
                f2[d] = fmaf(fv, w2S[k * 32 + role * 16 + d], f2[d]);
        }
        #pragma unroll
        for (int d = 0; d < 16; ++d) v = fmaf(f2[d], w3S[role * 16 + d], v);
    } else {
        float ec[8];
        #pragma unroll
        for (int q = 0; q < 8; ++q) ec[q] = bbS[q];
        for (int k = 0; k < 64; ++k) {
            float fv = f1e[k];
            #pragma unroll
            for (int q = 0; q < 8; ++q) ec[q] = fmaf(fv, wbS[k * 8 + q], ec[q]);
        }
        float fn = 0.f;
        #pragma unroll
        for (int q = 0; q < 8; ++q) fn = fmaf(ec[q], ec[q], fn);
        const int base = (role - 2) * 120;
        for (int i = 0; i < 120; ++i) {
            int cc = base + i;
            float dot = 0.f;
            #pragma unroll
            for (int q = 0; q < 8; ++q) dot = fmaf(ec[q], cbS[cc * 8 + q], dot);
            float d = fn + cnS[cc] - 2.f * dot;
            if (d < bd) { bd = d; bi = cc; }
        }
    }

    // reconverged: pairwise merges (role0<->1 for risk, role2<->3 for argmin)
    float vp = __shfl_xor(v, 1, 64);
    float od = __shfl_xor(bd, 1, 64);
    int   oi = __shfl_xor(bi, 1, 64);
    const int tok = tok0 + tl;
    if (role == 0) risk[tok] = sigmoidf_(v + vp + b3[0]);
    if (role == 2) {
        if (od < bd || (od == bd && oi < bi)) { bd = od; bi = oi; }
        idx_out[tok] = (float)bi;
        #pragma unroll
        for (int q = 0; q < 8; ++q)
            codes_out[(size_t)tok * 8 + q] = cbS[bi * 8 + q];
    }
}

// ---------------------------------------------------------------------------
__global__ __launch_bounds__(256)
void vn_kernel(const float* __restrict__ y, float* __restrict__ vn)
{
    const int tid = threadIdx.x;
    const int w = tid >> 6, j = tid & 63;
    const int t = blockIdx.x * 4 + w;
    const int tt = t & (TT - 1);
    const float4* cur = (const float4*)(y + (size_t)t * 256);
    const float4* prv = (const float4*)(y + (size_t)(tt == 0 ? t : t - 1) * 256);
    float4 a = cur[j], b = prv[j];
    float dx = a.x - b.x, dy = a.y - b.y, dz = a.z - b.z, dw = a.w - b.w;
    float ss = dx * dx + dy * dy + dz * dz + dw * dw;
    ss += __shfl_xor(ss, 1, 64);
    ss += __shfl_xor(ss, 2, 64);
    ss += __shfl_xor(ss, 4, 64);
    ss += __shfl_xor(ss, 8, 64);
    ss += __shfl_xor(ss, 16, 64);
    ss += __shfl_xor(ss, 32, 64);
    if (j == 0) vn[t] = sqrtf(ss);
}

__global__ __launch_bounds__(256)
void combined_kernel(const float* __restrict__ risk, const float* __restrict__ vn,
                     float* __restrict__ bif)
{
    const int t = blockIdx.x * 256 + threadIdx.x;
    const int tt = t & (TT - 1);
    float v = vn[t];
    float a = (tt == 0) ? 0.f : fabsf(v - vn[t - 1]);
    float cmb = 0.5f * risk[t] + 0.3f * sigmoidf_(v) + 0.2f * sigmoidf_(a);
    bif[t] = (cmb > 0.7f) ? 1.f : 0.f;
}

// ---------------------------------------------------------------------------
extern "C" void kernel_launch(void* const* d_in, const int* in_sizes, int n_in,
                              void* d_out, int out_size, void* d_ws, size_t ws_size,
                              hipStream_t stream)
{
    const float* x          = (const float*)d_in[0];
    const float* in_proj_w  = (const float*)d_in[1];
    const float* in_proj_b  = (const float*)d_in[2];
    const float* conv_w     = (const float*)d_in[3];
    const float* conv_b     = (const float*)d_in[4];
    const float* A_log      = (const float*)d_in[5];
    const float* bc_w       = (const float*)d_in[6];
    const float* bc_b       = (const float*)d_in[7];
    const float* dt_w       = (const float*)d_in[8];
    const float* dt_b       = (const float*)d_in[9];
    const float* out_w      = (const float*)d_in[10];
    const float* out_b      = (const float*)d_in[11];
    const float* cat1_w     = (const float*)d_in[12];
    const float* cat1_b     = (const float*)d_in[13];
    const float* cat2_w     = (const float*)d_in[14];
    const float* cat2_b     = (const float*)d_in[15];
    const float* risk_w     = (const float*)d_in[16];
    const float* risk_b     = (const float*)d_in[17];
    const float* e8a_w      = (const float*)d_in[18];
    const float* e8a_b      = (const float*)d_in[19];
    const float* e8b_w      = (const float*)d_in[20];
    const float* e8b_b      = (const float*)d_in[21];
    const float* codebook   = (const float*)d_in[22];

    float* out = (float*)d_out;
    float* y_out     = out;                        // [B,T,256]
    float* codes_out = out + (size_t)MTOK * 256;   // [B,T,8]
    float* idx_out   = codes_out + (size_t)MTOK * 8;
    float* bif_out   = idx_out + MTOK;

    // ---- choose batch-group count G (pure function of ws_size) ----
    const size_t AL = 255;
    #define ALN(x) (((x) + AL) & ~AL)
    size_t fixed_b = 2 * ALN((size_t)MTOK * 4)            // risk, vn
                   + 2 * ALN((size_t)MTOK * 256 * 2)      // xh, xl
                   + 2 * ALN((size_t)MTOK * 256 * 2)      // yh, yl
                   + ALN((size_t)MTOK * 128 * 4)          // F1
                   + 2 * ALN((size_t)1024 * 256 * 2)      // in_projT planes
                   + 2 * ALN((size_t)512 * 512 * 2)       // convT
                   + 2 * ALN((size_t)512 * 512 * 2)       // dtT
                   + 2 * ALN((size_t)128 * 512 * 2)       // bcT (padded)
                   + 2 * ALN((size_t)256 * 512 * 2)       // outT
                   + 2 * ALN((size_t)128 * 256 * 2)       // headT planes
                   + ALN((size_t)128 * 4);                // head bias
    int G = 8;
    {
        const int cand[4] = {1, 2, 4, 8};
        for (int i = 0; i < 4; ++i) {
            int g = cand[i];
            size_t Mg = (size_t)MTOK / g, Bg = BB / g;
            size_t grp = 2 * ALN(Mg * 512 * 2)            // MAIN/YG planes
                       + ALN(Mg * 512 * 4)                // GATE
                       + 2 * ALN(Mg * 512 * 2)            // XC planes
                       + ALN(Mg * 512 * 4)                // DT
                       + ALN(Mg * 32 * 4)                 // BC
                       + 2 * ALN(Bg * SCAN_NC * INNER * SS * 4); // P,H
            if (fixed_b + grp <= ws_size) { G = g; break; }
        }
    }
    const size_t Mg = (size_t)MTOK / G;
    const int    Bg = BB / G;

    char* p = (char*)d_ws;
    #define TAKE(T, name, bytes) T* name = (T*)p; p += ALN((size_t)(bytes));
    TAKE(float, risk, MTOK * 4)
    TAKE(float, vn,   MTOK * 4)
    TAKE(u16, xh, (size_t)MTOK * 256 * 2)
    TAKE(u16, xl, (size_t)MTOK * 256 * 2)
    TAKE(u16, yh, (size_t)MTOK * 256 * 2)
    TAKE(u16, yl, (size_t)MTOK * 256 * 2)
    TAKE(float, F1buf, (size_t)MTOK * 128 * 4)
    TAKE(u16, wiTh, (size_t)1024 * 256 * 2)
    TAKE(u16, wiTl, (size_t)1024 * 256 * 2)
    TAKE(u16, wcTh, (size_t)512 * 512 * 2)
    TAKE(u16, wcTl, (size_t)512 * 512 * 2)
    TAKE(u16, wdTh, (size_t)512 * 512 * 2)
    TAKE(u16, wdTl, (size_t)512 * 512 * 2)
    TAKE(u16, wbTh, (size_t)128 * 512 * 2)
    TAKE(u16, wbTl, (size_t)128 * 512 * 2)
    TAKE(u16, woTh, (size_t)256 * 512 * 2)
    TAKE(u16, woTl, (size_t)256 * 512 * 2)
    TAKE(u16, whTh, (size_t)128 * 256 * 2)
    TAKE(u16, whTl, (size_t)128 * 256 * 2)
    TAKE(float, hbias, 128 * 4)
    TAKE(u16, MAINh, Mg * 512 * 2)        // also YGh after scan
    TAKE(u16, MAINl, Mg * 512 * 2)        // also YGl
    TAKE(float, GATE, Mg * 512 * 4)
    TAKE(u16, XCh, Mg * 512 * 2)
    TAKE(u16, XCl, Mg * 512 * 2)
    TAKE(float, DT, Mg * 512 * 4)
    TAKE(float, BC, Mg * 32 * 4)
    TAKE(float, Pb, (size_t)Bg * SCAN_NC * INNER * SS * 4)
    TAKE(float, Hb, (size_t)Bg * SCAN_NC * INNER * SS * 4)

    // ---- one-time conversions ----
    split_kernel<<<(MTOK * 256 + 255) / 256, 256, 0, stream>>>(x, xh, xl, MTOK * 256);
    splitT_kernel<<<(1024 * 256 + 255) / 256, 256, 0, stream>>>(in_proj_w, wiTh, wiTl, 256, 1024, 1024);
    splitT_kernel<<<(512 * 512 + 255) / 256, 256, 0, stream>>>(conv_w, wcTh, wcTl, 512, 512, 512);
    splitT_kernel<<<(512 * 512 + 255) / 256, 256, 0, stream>>>(dt_w, wdTh, wdTl, 512, 512, 512);
    splitT_kernel<<<(128 * 512 + 255) / 256, 256, 0, stream>>>(bc_w, wbTh, wbTl, 512, 32, 128);
    splitT_kernel<<<(256 * 512 + 255) / 256, 256, 0, stream>>>(out_w, woTh, woTl, 512, 256, 256);
    headprep_kernel<<<128, 256, 0, stream>>>(cat1_w, cat1_b, e8a_w, e8a_b, whTh, whTl, hbias);

    for (int g = 0; g < G; ++g) {
        const u16* xgh = xh + (size_t)g * Mg * 256;
        const u16* xgl = xl + (size_t)g * Mg * 256;
        float* yg_out  = y_out + (size_t)g * Mg * 256;
        u16* ygh = yh + (size_t)g * Mg * 256;
        u16* ygl = yl + (size_t)g * Mg * 256;

        // 1. in_proj -> MAIN planes (cols 0-511) + GATE f32 (cols 512-1023)
        gemmS<0><<<dim3(8, Mg / 128), 256, 0, stream>>>(
            xgh, xgl, 256, wiTh, wiTl, in_proj_b, 1024, GATE, MAINh, MAINl);
        // 2. conv: silu -> XC planes
        gemmS<1><<<dim3(4, Mg / 128), 256, 0, stream>>>(
            MAINh, MAINl, 512, wcTh, wcTl, conv_b, 512, nullptr, XCh, XCl);
        // 3. dt: softplus -> DT f32
        gemmS<2><<<dim3(4, Mg / 128), 256, 0, stream>>>(
            XCh, XCl, 512, wdTh, wdTl, dt_b, 512, DT, nullptr, nullptr);
        // 4. bc -> BC f32 [Mg,32]
        gemmS<3><<<dim3(1, Mg / 128), 256, 0, stream>>>(
            XCh, XCl, 512, wbTh, wbTl, bc_b, 32, BC, nullptr, nullptr);
        // 5-7. chunked scan (register-state kernels)
        scan_pass1<<<Bg * SCAN_NC * 2, 256, 0, stream>>>(DT, XCh, XCl, BC, A_log, Pb, Hb);
        scan_pass2<<<Bg * 32, 256, 0, stream>>>(Pb, Hb);
        scan_pass3<<<Bg * SCAN_NC * 2, 256, 0, stream>>>(DT, XCh, XCl, BC, A_log, GATE,
                                                         Hb, MAINh, MAINl);
        // 8. out_proj -> y f32 (d_out) + y bf16 planes
        gemmS<4><<<dim3(2, Mg / 128), 256, 0, stream>>>(
            MAINh, MAINl, 512, woTh, woTl, out_b, 256, yg_out, ygh, ygl);
    }

    // ---- heads on full y ----
    gemmS<5><<<dim3(1, MTOK / 128), 256, 0, stream>>>(
        yh, yl, 256, whTh, whTl, hbias, 128, F1buf, nullptr, nullptr);
    head_finish<<<MTOK / 64, 256, 0, stream>>>(F1buf, cat2_w, cat2_b, risk_w, risk_b,
                                               e8b_w, e8b_b, codebook,
                                               risk, codes_out, idx_out);
    vn_kernel<<<MTOK / 4, 256, 0, stream>>>(y_out, vn);
    combined_kernel<<<MTOK / 256, 256, 0, stream>>>(risk, vn, bif_out);
}